// Round 8
// baseline (216.380 us; speedup 1.0000x reference)
//
#include <hip/hip_runtime.h>

typedef unsigned short ushort_t;
typedef __bf16 bf16x8 __attribute__((ext_vector_type(8)));
typedef float  f32x4  __attribute__((ext_vector_type(4)));

#define MFMA16(a,b,c) __builtin_amdgcn_mfma_f32_16x16x32_bf16((a),(b),(c),0,0,0)

__device__ __forceinline__ ushort_t f2bf(float f) {
    union { float f; unsigned u; } x; x.f = f;
    unsigned r = (x.u + 0x7fffu + ((x.u >> 16) & 1u)) >> 16;
    return (ushort_t)r;
}

__device__ __forceinline__ void gload16(const ushort_t* g, char* l) {
    __builtin_amdgcn_global_load_lds(
        (const __attribute__((address_space(1))) unsigned*)g,
        (__attribute__((address_space(3))) unsigned*)l, 16, 0, 0);
}

// ---------------- all casts in one launch ----------------
__global__ void cast_all(const float* __restrict__ x,
                         const float* __restrict__ Wq, const float* __restrict__ Wk,
                         const float* __restrict__ Wv, const float* __restrict__ Wo,
                         ushort_t* __restrict__ xbf, ushort_t* __restrict__ wqkv,
                         ushort_t* __restrict__ wob) {
    int i = blockIdx.x * 256 + threadIdx.x;
    float4 v;
    if (i < 1048576) {
        v = ((const float4*)x)[i];
        ushort4 o;
        o.x = f2bf(v.x); o.y = f2bf(v.y); o.z = f2bf(v.z); o.w = f2bf(v.w);
        ((ushort4*)xbf)[i] = o;
    } else {
        int j = i - 1048576;
        int r = j >> 18, jj = j & 0x3ffff;
        const float* src = (r == 0) ? Wq : (r == 1) ? Wk : (r == 2) ? Wv : Wo;
        v = ((const float4*)src)[jj];
        ushort4 o;
        o.x = f2bf(v.x); o.y = f2bf(v.y); o.z = f2bf(v.z); o.w = f2bf(v.w);
        if (r < 3) ((ushort4*)wqkv)[(size_t)r*262144 + jj] = o;
        else       ((ushort4*)wob)[jj] = o;
    }
}

// ---------------- GEMM: C[m,n] = sum_k A[m,k]*W[n,k] (+bias) ----------------
template<int MODE>
__global__ void gemm_bt(const ushort_t* __restrict__ A,
                        const ushort_t* __restrict__ Bw,
                        const float* __restrict__ b0, const float* __restrict__ b1,
                        const float* __restrict__ b2,
                        void* __restrict__ C0, void* __restrict__ C1,
                        void* __restrict__ C2, void* __restrict__ C3,
                        void* __restrict__ C4)
{
    __shared__ __align__(16) char lds[32768];
    char* As = lds;
    char* Bs = lds + 16384;
    const int tid  = threadIdx.x;
    const int lane = tid & 63;
    const int wid  = tid >> 6;
    const int wrow = wid >> 1;
    const int wcol = wid & 1;
    const int m0 = blockIdx.x * 128;
    const int n0 = blockIdx.y * 128;

    f32x4 acc[4][4] = {};

    #define STAGE(kb)                                                          \
        _Pragma("unroll")                                                      \
        for (int k = 0; k < 4; ++k) {                                          \
            int idx = k*256 + tid;                                             \
            int row = idx >> 3, s = idx & 7;                                   \
            int sc = s ^ (row & 7);                                            \
            gload16(A  + (size_t)(m0+row)*1024 + (kb) + sc*8, As + idx*16);    \
            gload16(Bw + (size_t)(n0+row)*1024 + (kb) + sc*8, Bs + idx*16);    \
        }

    STAGE(0)
    for (int kt = 0; kt < 16; ++kt) {
        __syncthreads();
        #pragma unroll
        for (int ks = 0; ks < 2; ++ks) {
            bf16x8 af[4], bfr[4];
            #pragma unroll
            for (int i = 0; i < 4; ++i) {
                int row = wrow*64 + i*16 + (lane & 15);
                int sl  = ks*4 + (lane >> 4);
                af[i] = *(const bf16x8*)(As + row*128 + ((sl ^ (row & 7)) << 4));
            }
            #pragma unroll
            for (int j = 0; j < 4; ++j) {
                int row = wcol*64 + j*16 + (lane & 15);
                int sl  = ks*4 + (lane >> 4);
                bfr[j] = *(const bf16x8*)(Bs + row*128 + ((sl ^ (row & 7)) << 4));
            }
            #pragma unroll
            for (int i = 0; i < 4; ++i)
                #pragma unroll
                for (int j = 0; j < 4; ++j)
                    acc[i][j] = MFMA16(af[i], bfr[j], acc[i][j]);
        }
        __syncthreads();
        if (kt < 15) STAGE((kt+1)*64)
    }
    #undef STAGE

    #pragma unroll
    for (int i = 0; i < 4; ++i) {
        #pragma unroll
        for (int j = 0; j < 4; ++j) {
            #pragma unroll
            for (int q = 0; q < 4; ++q) {
                int gm = m0 + wrow*64 + i*16 + (lane >> 4)*4 + q;
                int gn = n0 + wcol*64 + j*16 + (lane & 15);
                if (MODE == 1) {
                    ((float*)C0)[(size_t)gm*1024 + gn] = acc[i][j][q] + b0[gn];
                } else {
                    int reg = gn >> 10, nn = gn & 1023;
                    float bias = ((reg == 0) ? b0 : (reg == 1) ? b1 : b2)[nn];
                    float v = acc[i][j][q] + bias;
                    int b = gm >> 11, s = gm & 2047;
                    int h = nn >> 6,  dk = nn & 63;
                    int hh = b*16 + h;
                    ushort_t bv = f2bf(v);
                    if (reg == 0) {
                        ((ushort_t*)C0)[((size_t)hh*2048 + s)*64 + dk] = bv;           // Qb
                    } else if (reg == 1) {
                        ((ushort_t*)C1)[((size_t)hh*2048 + s)*64 + dk] = bv;           // Kn
                        ((ushort_t*)C2)[(((size_t)hh*4 + (s & 3))*512 + (s >> 2))*64 + dk] = bv; // Kss
                    } else {
                        ((ushort_t*)C3)[((size_t)hh*64 + dk)*2048 + s] = bv;           // Vtn
                        ((ushort_t*)C4)[(((size_t)hh*4 + (s & 3))*64 + dk)*512 + (s >> 2)] = bv; // Vts
                    }
                }
            }
        }
    }
}

// ---------------- sparse flash attention v5: v4 + residency cap ----------------
// SINGLE CHANGE vs v4: LDS padded 8KB -> 56KB so only 2 WGs fit per CU.
// Theory (r7 post-mortem): at 3.5 WGs/CU, ~3.5 heads' K/V panels (4.4MB) were
// resident per XCD > 4MB L2 -> streaming eviction -> FETCH 190MB and a
// latency-bound kernel. At 2 WGs/CU: 2 heads = 2.5MB < 4MB -> L2 reuse returns.
__global__ void sparse_attn5(const ushort_t* __restrict__ Qg,
                             const ushort_t* __restrict__ Kn,
                             const ushort_t* __restrict__ Kss,
                             const ushort_t* __restrict__ Vtn,
                             const ushort_t* __restrict__ Vts,
                             ushort_t* __restrict__ attn)
{
    __shared__ __align__(16) char Ps[57344];   // first 8KB used; rest = occupancy cap
    const int tid  = threadIdx.x;
    const int lane = tid & 63;
    const int r    = tid >> 6;
    const int l15  = lane & 15;
    const int lhi  = lane >> 4;
    const int id2  = (blockIdx.x & 7)*128 + (blockIdx.x >> 3);
    const int bh   = id2 >> 5;
    const int rb   = id2 & 31;
    char* Pw = Ps + r*2048;

    bf16x8 aq[2];
    {
        const ushort_t* qp = Qg + ((size_t)bh*2048 + rb*64 + r + 4*l15)*64 + lhi*8;
        aq[0] = *(const bf16x8*)(qp);
        aq[1] = *(const bf16x8*)(qp + 32);
    }

    float tsum[4] = {0.f, 0.f, 0.f, 0.f};
    f32x4 oacc[4] = {};

    // ---- Pass 1: 512 strided columns, unmasked, 8 chunks ----
    const ushort_t* Kst = Kss + ((size_t)bh*4 + r)*512*64;
    const ushort_t* Vst = Vts + ((size_t)bh*4 + r)*64*512;

    bf16x8 kc[8];
    #pragma unroll
    for (int ks = 0; ks < 2; ++ks)
        #pragma unroll
        for (int n = 0; n < 4; ++n)
            kc[ks*4+n] = *(const bf16x8*)(Kst + (size_t)(n*16 + l15)*64 + ks*32 + lhi*8);

    for (int c = 0; c < 8; ++c) {
        const int t0 = c*64;
        bf16x8 vc[8];
        #pragma unroll
        for (int ks = 0; ks < 2; ++ks)
            #pragma unroll
            for (int d = 0; d < 4; ++d)
                vc[ks*4+d] = *(const bf16x8*)(Vst + (size_t)(d*16 + l15)*512 + t0 + ks*32 + lhi*8);
        f32x4 sacc[4] = {};
        #pragma unroll
        for (int ks = 0; ks < 2; ++ks)
            #pragma unroll
            for (int n = 0; n < 4; ++n)
                sacc[n] = MFMA16(aq[ks], kc[ks*4+n], sacc[n]);
        bf16x8 kn2[8];
        if (c < 7) {
            #pragma unroll
            for (int ks = 0; ks < 2; ++ks)
                #pragma unroll
                for (int n = 0; n < 4; ++n)
                    kn2[ks*4+n] = *(const bf16x8*)(Kst + (size_t)(t0 + 64 + n*16 + l15)*64 + ks*32 + lhi*8);
        }
        #pragma unroll
        for (int n = 0; n < 4; ++n) {
            int colb = (n*16 + l15) * 2;
            #pragma unroll
            for (int q = 0; q < 4; ++q) {
                float p = __expf(sacc[n][q]*0.125f - 16.f);
                tsum[q] += p;
                int rowp = lhi*4 + q;
                *(__bf16*)(Pw + rowp*128 + (colb ^ ((rowp & 7) << 4))) = (__bf16)p;
            }
        }
        #pragma unroll
        for (int ks = 0; ks < 2; ++ks) {
            int sl = ks*4 + lhi;
            bf16x8 pf = *(const bf16x8*)(Pw + l15*128 + ((sl ^ (l15 & 7)) << 4));
            #pragma unroll
            for (int d = 0; d < 4; ++d)
                oacc[d] = MFMA16(pf, vc[ks*4+d], oacc[d]);
        }
        if (c < 7) {
            #pragma unroll
            for (int t = 0; t < 8; ++t) kc[t] = kn2[t];
        }
    }

    // ---- Pass 2: local window minus strided ----
    const int bl0 = (rb > 0)  ? rb-1 : 0;
    const int bl1 = (rb < 31) ? rb+1 : 31;
    const bool notstr = ((l15 & 3) != r);
    for (int bl = bl0; bl <= bl1; ++bl) {
        bf16x8 vc[8];
        #pragma unroll
        for (int ks = 0; ks < 2; ++ks)
            #pragma unroll
            for (int d = 0; d < 4; ++d)
                vc[ks*4+d] = *(const bf16x8*)(Vtn + ((size_t)bh*64 + d*16 + l15)*2048 + bl*64 + ks*32 + lhi*8);
        f32x4 sacc[4] = {};
        #pragma unroll
        for (int ks = 0; ks < 2; ++ks) {
            bf16x8 bk[4];
            #pragma unroll
            for (int n = 0; n < 4; ++n)
                bk[n] = *(const bf16x8*)(Kn + ((size_t)bh*2048 + bl*64 + n*16 + l15)*64 + ks*32 + lhi*8);
            #pragma unroll
            for (int n = 0; n < 4; ++n)
                sacc[n] = MFMA16(aq[ks], bk[n], sacc[n]);
        }
        #pragma unroll
        for (int n = 0; n < 4; ++n) {
            int j = bl*64 + n*16 + l15;
            int colb = (n*16 + l15) * 2;
            #pragma unroll
            for (int q = 0; q < 4; ++q) {
                int i = rb*64 + r + 16*lhi + 4*q;
                int d = j - i;
                bool valid = notstr && (d <= 32) && (d >= -32);
                float sv = valid ? sacc[n][q]*0.125f : -1e30f;
                float p = __expf(sv - 16.f);
                tsum[q] += p;
                int rowp = lhi*4 + q;
                *(__bf16*)(Pw + rowp*128 + (colb ^ ((rowp & 7) << 4))) = (__bf16)p;
            }
        }
        #pragma unroll
        for (int ks = 0; ks < 2; ++ks) {
            int sl = ks*4 + lhi;
            bf16x8 pf = *(const bf16x8*)(Pw + l15*128 + ((sl ^ (l15 & 7)) << 4));
            #pragma unroll
            for (int d = 0; d < 4; ++d)
                oacc[d] = MFMA16(pf, vc[ks*4+d], oacc[d]);
        }
    }

    // ---- epilogue: single deferred row-sum reduction + normalize ----
    const int b = bh >> 4, h = bh & 15;
    f32x4 invv;
    #pragma unroll
    for (int q = 0; q < 4; ++q) {
        float t = tsum[q];
        t += __shfl_xor(t, 1);
        t += __shfl_xor(t, 2);
        t += __shfl_xor(t, 4);
        t += __shfl_xor(t, 8);
        invv[q] = 1.f / t;
    }
    #pragma unroll
    for (int d = 0; d < 4; ++d) {
        f32x4 o = oacc[d] * invv;
        #pragma unroll
        for (int q = 0; q < 4; ++q) {
            int srow = rb*64 + r + 16*lhi + 4*q;
            int gr = b*2048 + srow;
            int gc = h*64 + d*16 + l15;
            attn[(size_t)gr*1024 + gc] = f2bf(o[q]);
        }
    }
}

extern "C" void kernel_launch(void* const* d_in, const int* in_sizes, int n_in,
                              void* d_out, int out_size, void* d_ws, size_t ws_size,
                              hipStream_t stream)
{
    const float* x  = (const float*)d_in[0];
    const float* Wq = (const float*)d_in[1];
    const float* bq = (const float*)d_in[2];
    const float* Wk = (const float*)d_in[3];
    const float* bk = (const float*)d_in[4];
    const float* Wv = (const float*)d_in[5];
    const float* bv = (const float*)d_in[6];
    const float* Wo = (const float*)d_in[7];
    const float* bo = (const float*)d_in[8];

    char* ws = (char*)d_ws;
    ushort_t* xbf  = (ushort_t*)(ws);                        // 8 MB
    ushort_t* wqkv = (ushort_t*)(ws + ((size_t)8  << 20));   // 6 MB [3072][1024]
    ushort_t* wob  = (ushort_t*)(ws + ((size_t)14 << 20));   // 2 MB
    ushort_t* Qb   = (ushort_t*)(ws + ((size_t)16 << 20));   // 8 MB [BH,S,Dk]
    ushort_t* Kn   = (ushort_t*)(ws + ((size_t)24 << 20));   // 8 MB [BH,S,Dk]
    ushort_t* Kss  = (ushort_t*)(ws + ((size_t)32 << 20));   // 8 MB [BH,4,512,64]
    ushort_t* Vtn  = (ushort_t*)(ws + ((size_t)40 << 20));   // 8 MB [BH,Dk,S]
    ushort_t* Vts  = (ushort_t*)(ws + ((size_t)48 << 20));   // 8 MB [BH,4,64,512]
    ushort_t* attn = (ushort_t*)(ws + ((size_t)56 << 20));   // 8 MB

    cast_all<<<8192, 256, 0, stream>>>(x, Wq, Wk, Wv, Wo, xbf, wqkv, wob);

    gemm_bt<0><<<dim3(32, 24), 256, 0, stream>>>(xbf, wqkv, bq, bk, bv,
                                                 Qb, Kn, Kss, Vtn, Vts);

    sparse_attn5<<<dim3(1024), 256, 0, stream>>>(Qb, Kn, Kss, Vtn, Vts, attn);

    gemm_bt<1><<<dim3(32, 8), 256, 0, stream>>>(attn, wob, bo, nullptr, nullptr,
                                                d_out, nullptr, nullptr, nullptr, nullptr);
}

// Round 9
// 157.150 us; speedup vs baseline: 1.3769x; 1.3769x over previous
//
#include <hip/hip_runtime.h>

typedef unsigned short ushort_t;
typedef __bf16 bf16x8 __attribute__((ext_vector_type(8)));
typedef float  f32x4  __attribute__((ext_vector_type(4)));

#define MFMA16(a,b,c) __builtin_amdgcn_mfma_f32_16x16x32_bf16((a),(b),(c),0,0,0)

__device__ __forceinline__ ushort_t f2bf(float f) {
    union { float f; unsigned u; } x; x.f = f;
    unsigned r = (x.u + 0x7fffu + ((x.u >> 16) & 1u)) >> 16;
    return (ushort_t)r;
}

__device__ __forceinline__ void gload16(const ushort_t* g, char* l) {
    __builtin_amdgcn_global_load_lds(
        (const __attribute__((address_space(1))) unsigned*)g,
        (__attribute__((address_space(3))) unsigned*)l, 16, 0, 0);
}

// ---------------- all casts in one launch ----------------
__global__ void cast_all(const float* __restrict__ x,
                         const float* __restrict__ Wq, const float* __restrict__ Wk,
                         const float* __restrict__ Wv, const float* __restrict__ Wo,
                         ushort_t* __restrict__ xbf, ushort_t* __restrict__ wqkv,
                         ushort_t* __restrict__ wob) {
    int i = blockIdx.x * 256 + threadIdx.x;
    float4 v;
    if (i < 1048576) {
        v = ((const float4*)x)[i];
        ushort4 o;
        o.x = f2bf(v.x); o.y = f2bf(v.y); o.z = f2bf(v.z); o.w = f2bf(v.w);
        ((ushort4*)xbf)[i] = o;
    } else {
        int j = i - 1048576;
        int r = j >> 18, jj = j & 0x3ffff;
        const float* src = (r == 0) ? Wq : (r == 1) ? Wk : (r == 2) ? Wv : Wo;
        v = ((const float4*)src)[jj];
        ushort4 o;
        o.x = f2bf(v.x); o.y = f2bf(v.y); o.z = f2bf(v.z); o.w = f2bf(v.w);
        if (r < 3) ((ushort4*)wqkv)[(size_t)r*262144 + jj] = o;
        else       ((ushort4*)wob)[jj] = o;
    }
}

// ---------------- GEMM: C[m,n] = sum_k A[m,k]*W[n,k] (+bias) ----------------
template<int MODE>
__global__ void gemm_bt(const ushort_t* __restrict__ A,
                        const ushort_t* __restrict__ Bw,
                        const float* __restrict__ b0, const float* __restrict__ b1,
                        const float* __restrict__ b2,
                        void* __restrict__ C0, void* __restrict__ C1,
                        void* __restrict__ C2, void* __restrict__ C3,
                        void* __restrict__ C4)
{
    __shared__ __align__(16) char lds[32768];
    char* As = lds;
    char* Bs = lds + 16384;
    const int tid  = threadIdx.x;
    const int lane = tid & 63;
    const int wid  = tid >> 6;
    const int wrow = wid >> 1;
    const int wcol = wid & 1;
    const int m0 = blockIdx.x * 128;
    const int n0 = blockIdx.y * 128;

    f32x4 acc[4][4] = {};

    #define STAGE(kb)                                                          \
        _Pragma("unroll")                                                      \
        for (int k = 0; k < 4; ++k) {                                          \
            int idx = k*256 + tid;                                             \
            int row = idx >> 3, s = idx & 7;                                   \
            int sc = s ^ (row & 7);                                            \
            gload16(A  + (size_t)(m0+row)*1024 + (kb) + sc*8, As + idx*16);    \
            gload16(Bw + (size_t)(n0+row)*1024 + (kb) + sc*8, Bs + idx*16);    \
        }

    STAGE(0)
    for (int kt = 0; kt < 16; ++kt) {
        __syncthreads();
        #pragma unroll
        for (int ks = 0; ks < 2; ++ks) {
            bf16x8 af[4], bfr[4];
            #pragma unroll
            for (int i = 0; i < 4; ++i) {
                int row = wrow*64 + i*16 + (lane & 15);
                int sl  = ks*4 + (lane >> 4);
                af[i] = *(const bf16x8*)(As + row*128 + ((sl ^ (row & 7)) << 4));
            }
            #pragma unroll
            for (int j = 0; j < 4; ++j) {
                int row = wcol*64 + j*16 + (lane & 15);
                int sl  = ks*4 + (lane >> 4);
                bfr[j] = *(const bf16x8*)(Bs + row*128 + ((sl ^ (row & 7)) << 4));
            }
            #pragma unroll
            for (int i = 0; i < 4; ++i)
                #pragma unroll
                for (int j = 0; j < 4; ++j)
                    acc[i][j] = MFMA16(af[i], bfr[j], acc[i][j]);
        }
        __syncthreads();
        if (kt < 15) STAGE((kt+1)*64)
    }
    #undef STAGE

    #pragma unroll
    for (int i = 0; i < 4; ++i) {
        #pragma unroll
        for (int j = 0; j < 4; ++j) {
            #pragma unroll
            for (int q = 0; q < 4; ++q) {
                int gm = m0 + wrow*64 + i*16 + (lane >> 4)*4 + q;
                int gn = n0 + wcol*64 + j*16 + (lane & 15);
                if (MODE == 1) {
                    ((float*)C0)[(size_t)gm*1024 + gn] = acc[i][j][q] + b0[gn];
                } else {
                    int reg = gn >> 10, nn = gn & 1023;
                    float bias = ((reg == 0) ? b0 : (reg == 1) ? b1 : b2)[nn];
                    float v = acc[i][j][q] + bias;
                    int b = gm >> 11, s = gm & 2047;
                    int h = nn >> 6,  dk = nn & 63;
                    int hh = b*16 + h;
                    ushort_t bv = f2bf(v);
                    if (reg == 0) {
                        ((ushort_t*)C0)[((size_t)hh*2048 + s)*64 + dk] = bv;           // Qb
                    } else if (reg == 1) {
                        ((ushort_t*)C1)[((size_t)hh*2048 + s)*64 + dk] = bv;           // Kn
                        ((ushort_t*)C2)[(((size_t)hh*4 + (s & 3))*512 + (s >> 2))*64 + dk] = bv; // Kss
                    } else {
                        ((ushort_t*)C3)[((size_t)hh*64 + dk)*2048 + s] = bv;           // Vtn
                        ((ushort_t*)C4)[(((size_t)hh*4 + (s & 3))*64 + dk)*512 + (s >> 2)] = bv; // Vts
                    }
                }
            }
        }
    }
}

// ---------------- sparse flash attention v6: v4 + 256-VGPR budget ----------------
// SINGLE CHANGE vs r7's v4: __launch_bounds__(256, 2) -> 256-VGPR budget, so the
// prefetch arrays (aq+kc+kn2+vc+sacc+oacc ~ 150 VGPR) live in registers instead
// of scratch. r8 diagnosis: VGPR_Count=64 (compiler targeted 8 waves/SIMD) =>
// per-iteration scratch spills = 313MB HBM writes + ~130MB re-reads. 2 waves/EU
// also caps residency at 2 WGs/CU (2 heads = 2.5MB < 4MB L2/XCD).
__global__ __launch_bounds__(256, 2)
void sparse_attn6(const ushort_t* __restrict__ Qg,
                  const ushort_t* __restrict__ Kn,
                  const ushort_t* __restrict__ Kss,
                  const ushort_t* __restrict__ Vtn,
                  const ushort_t* __restrict__ Vts,
                  ushort_t* __restrict__ attn)
{
    __shared__ __align__(16) char Ps[8192];
    const int tid  = threadIdx.x;
    const int lane = tid & 63;
    const int r    = tid >> 6;
    const int l15  = lane & 15;
    const int lhi  = lane >> 4;
    const int id2  = (blockIdx.x & 7)*128 + (blockIdx.x >> 3);
    const int bh   = id2 >> 5;
    const int rb   = id2 & 31;
    char* Pw = Ps + r*2048;

    bf16x8 aq[2];
    {
        const ushort_t* qp = Qg + ((size_t)bh*2048 + rb*64 + r + 4*l15)*64 + lhi*8;
        aq[0] = *(const bf16x8*)(qp);
        aq[1] = *(const bf16x8*)(qp + 32);
    }

    float tsum[4] = {0.f, 0.f, 0.f, 0.f};
    f32x4 oacc[4] = {};

    // ---- Pass 1: 512 strided columns, unmasked, 8 chunks ----
    const ushort_t* Kst = Kss + ((size_t)bh*4 + r)*512*64;
    const ushort_t* Vst = Vts + ((size_t)bh*4 + r)*64*512;

    bf16x8 kc[8];
    #pragma unroll
    for (int ks = 0; ks < 2; ++ks)
        #pragma unroll
        for (int n = 0; n < 4; ++n)
            kc[ks*4+n] = *(const bf16x8*)(Kst + (size_t)(n*16 + l15)*64 + ks*32 + lhi*8);

    for (int c = 0; c < 8; ++c) {
        const int t0 = c*64;
        bf16x8 vc[8];
        #pragma unroll
        for (int ks = 0; ks < 2; ++ks)
            #pragma unroll
            for (int d = 0; d < 4; ++d)
                vc[ks*4+d] = *(const bf16x8*)(Vst + (size_t)(d*16 + l15)*512 + t0 + ks*32 + lhi*8);
        f32x4 sacc[4] = {};
        #pragma unroll
        for (int ks = 0; ks < 2; ++ks)
            #pragma unroll
            for (int n = 0; n < 4; ++n)
                sacc[n] = MFMA16(aq[ks], kc[ks*4+n], sacc[n]);
        bf16x8 kn2[8];
        if (c < 7) {
            #pragma unroll
            for (int ks = 0; ks < 2; ++ks)
                #pragma unroll
                for (int n = 0; n < 4; ++n)
                    kn2[ks*4+n] = *(const bf16x8*)(Kst + (size_t)(t0 + 64 + n*16 + l15)*64 + ks*32 + lhi*8);
        }
        #pragma unroll
        for (int n = 0; n < 4; ++n) {
            int colb = (n*16 + l15) * 2;
            #pragma unroll
            for (int q = 0; q < 4; ++q) {
                float p = __expf(sacc[n][q]*0.125f - 16.f);
                tsum[q] += p;
                int rowp = lhi*4 + q;
                *(__bf16*)(Pw + rowp*128 + (colb ^ ((rowp & 7) << 4))) = (__bf16)p;
            }
        }
        #pragma unroll
        for (int ks = 0; ks < 2; ++ks) {
            int sl = ks*4 + lhi;
            bf16x8 pf = *(const bf16x8*)(Pw + l15*128 + ((sl ^ (l15 & 7)) << 4));
            #pragma unroll
            for (int d = 0; d < 4; ++d)
                oacc[d] = MFMA16(pf, vc[ks*4+d], oacc[d]);
        }
        if (c < 7) {
            #pragma unroll
            for (int t = 0; t < 8; ++t) kc[t] = kn2[t];
        }
    }

    // ---- Pass 2: local window minus strided ----
    const int bl0 = (rb > 0)  ? rb-1 : 0;
    const int bl1 = (rb < 31) ? rb+1 : 31;
    const bool notstr = ((l15 & 3) != r);
    for (int bl = bl0; bl <= bl1; ++bl) {
        bf16x8 vc[8];
        #pragma unroll
        for (int ks = 0; ks < 2; ++ks)
            #pragma unroll
            for (int d = 0; d < 4; ++d)
                vc[ks*4+d] = *(const bf16x8*)(Vtn + ((size_t)bh*64 + d*16 + l15)*2048 + bl*64 + ks*32 + lhi*8);
        f32x4 sacc[4] = {};
        #pragma unroll
        for (int ks = 0; ks < 2; ++ks) {
            bf16x8 bk[4];
            #pragma unroll
            for (int n = 0; n < 4; ++n)
                bk[n] = *(const bf16x8*)(Kn + ((size_t)bh*2048 + bl*64 + n*16 + l15)*64 + ks*32 + lhi*8);
            #pragma unroll
            for (int n = 0; n < 4; ++n)
                sacc[n] = MFMA16(aq[ks], bk[n], sacc[n]);
        }
        #pragma unroll
        for (int n = 0; n < 4; ++n) {
            int j = bl*64 + n*16 + l15;
            int colb = (n*16 + l15) * 2;
            #pragma unroll
            for (int q = 0; q < 4; ++q) {
                int i = rb*64 + r + 16*lhi + 4*q;
                int d = j - i;
                bool valid = notstr && (d <= 32) && (d >= -32);
                float sv = valid ? sacc[n][q]*0.125f : -1e30f;
                float p = __expf(sv - 16.f);
                tsum[q] += p;
                int rowp = lhi*4 + q;
                *(__bf16*)(Pw + rowp*128 + (colb ^ ((rowp & 7) << 4))) = (__bf16)p;
            }
        }
        #pragma unroll
        for (int ks = 0; ks < 2; ++ks) {
            int sl = ks*4 + lhi;
            bf16x8 pf = *(const bf16x8*)(Pw + l15*128 + ((sl ^ (l15 & 7)) << 4));
            #pragma unroll
            for (int d = 0; d < 4; ++d)
                oacc[d] = MFMA16(pf, vc[ks*4+d], oacc[d]);
        }
    }

    // ---- epilogue: single deferred row-sum reduction + normalize ----
    const int b = bh >> 4, h = bh & 15;
    f32x4 invv;
    #pragma unroll
    for (int q = 0; q < 4; ++q) {
        float t = tsum[q];
        t += __shfl_xor(t, 1);
        t += __shfl_xor(t, 2);
        t += __shfl_xor(t, 4);
        t += __shfl_xor(t, 8);
        invv[q] = 1.f / t;
    }
    #pragma unroll
    for (int d = 0; d < 4; ++d) {
        f32x4 o = oacc[d] * invv;
        #pragma unroll
        for (int q = 0; q < 4; ++q) {
            int srow = rb*64 + r + 16*lhi + 4*q;
            int gr = b*2048 + srow;
            int gc = h*64 + d*16 + l15;
            attn[(size_t)gr*1024 + gc] = f2bf(o[q]);
        }
    }
}

extern "C" void kernel_launch(void* const* d_in, const int* in_sizes, int n_in,
                              void* d_out, int out_size, void* d_ws, size_t ws_size,
                              hipStream_t stream)
{
    const float* x  = (const float*)d_in[0];
    const float* Wq = (const float*)d_in[1];
    const float* bq = (const float*)d_in[2];
    const float* Wk = (const float*)d_in[3];
    const float* bk = (const float*)d_in[4];
    const float* Wv = (const float*)d_in[5];
    const float* bv = (const float*)d_in[6];
    const float* Wo = (const float*)d_in[7];
    const float* bo = (const float*)d_in[8];

    char* ws = (char*)d_ws;
    ushort_t* xbf  = (ushort_t*)(ws);                        // 8 MB
    ushort_t* wqkv = (ushort_t*)(ws + ((size_t)8  << 20));   // 6 MB [3072][1024]
    ushort_t* wob  = (ushort_t*)(ws + ((size_t)14 << 20));   // 2 MB
    ushort_t* Qb   = (ushort_t*)(ws + ((size_t)16 << 20));   // 8 MB [BH,S,Dk]
    ushort_t* Kn   = (ushort_t*)(ws + ((size_t)24 << 20));   // 8 MB [BH,S,Dk]
    ushort_t* Kss  = (ushort_t*)(ws + ((size_t)32 << 20));   // 8 MB [BH,4,512,64]
    ushort_t* Vtn  = (ushort_t*)(ws + ((size_t)40 << 20));   // 8 MB [BH,Dk,S]
    ushort_t* Vts  = (ushort_t*)(ws + ((size_t)48 << 20));   // 8 MB [BH,4,64,512]
    ushort_t* attn = (ushort_t*)(ws + ((size_t)56 << 20));   // 8 MB

    cast_all<<<8192, 256, 0, stream>>>(x, Wq, Wk, Wv, Wo, xbf, wqkv, wob);

    gemm_bt<0><<<dim3(32, 24), 256, 0, stream>>>(xbf, wqkv, bq, bk, bv,
                                                 Qb, Kn, Kss, Vtn, Vts);

    sparse_attn6<<<dim3(1024), 256, 0, stream>>>(Qb, Kn, Kss, Vtn, Vts, attn);

    gemm_bt<1><<<dim3(32, 8), 256, 0, stream>>>(attn, wob, bo, nullptr, nullptr,
                                                d_out, nullptr, nullptr, nullptr, nullptr);
}

// Round 10
// 109.437 us; speedup vs baseline: 1.9772x; 1.4360x over previous
//
#include <hip/hip_runtime.h>

typedef unsigned short ushort_t;
typedef __bf16 bf16x8 __attribute__((ext_vector_type(8)));
typedef float  f32x4  __attribute__((ext_vector_type(4)));

#define MFMA16(a,b,c) __builtin_amdgcn_mfma_f32_16x16x32_bf16((a),(b),(c),0,0,0)

__device__ __forceinline__ ushort_t f2bf(float f) {
    union { float f; unsigned u; } x; x.f = f;
    unsigned r = (x.u + 0x7fffu + ((x.u >> 16) & 1u)) >> 16;
    return (ushort_t)r;
}

__device__ __forceinline__ void gload16(const ushort_t* g, char* l) {
    __builtin_amdgcn_global_load_lds(
        (const __attribute__((address_space(1))) unsigned*)g,
        (__attribute__((address_space(3))) unsigned*)l, 16, 0, 0);
}

// ---------------- all casts in one launch ----------------
__global__ void cast_all(const float* __restrict__ x,
                         const float* __restrict__ Wq, const float* __restrict__ Wk,
                         const float* __restrict__ Wv, const float* __restrict__ Wo,
                         ushort_t* __restrict__ xbf, ushort_t* __restrict__ wqkv,
                         ushort_t* __restrict__ wob) {
    int i = blockIdx.x * 256 + threadIdx.x;
    float4 v;
    if (i < 1048576) {
        v = ((const float4*)x)[i];
        ushort4 o;
        o.x = f2bf(v.x); o.y = f2bf(v.y); o.z = f2bf(v.z); o.w = f2bf(v.w);
        ((ushort4*)xbf)[i] = o;
    } else {
        int j = i - 1048576;
        int r = j >> 18, jj = j & 0x3ffff;
        const float* src = (r == 0) ? Wq : (r == 1) ? Wk : (r == 2) ? Wv : Wo;
        v = ((const float4*)src)[jj];
        ushort4 o;
        o.x = f2bf(v.x); o.y = f2bf(v.y); o.z = f2bf(v.z); o.w = f2bf(v.w);
        if (r < 3) ((ushort4*)wqkv)[(size_t)r*262144 + jj] = o;
        else       ((ushort4*)wob)[jj] = o;
    }
}

// ---------------- GEMM: C[m,n] = sum_k A[m,k]*W[n,k] (+bias) ----------------
template<int MODE>
__global__ void gemm_bt(const ushort_t* __restrict__ A,
                        const ushort_t* __restrict__ Bw,
                        const float* __restrict__ b0, const float* __restrict__ b1,
                        const float* __restrict__ b2,
                        void* __restrict__ C0, void* __restrict__ C1,
                        void* __restrict__ C2, void* __restrict__ C3,
                        void* __restrict__ C4)
{
    __shared__ __align__(16) char lds[32768];
    char* As = lds;
    char* Bs = lds + 16384;
    const int tid  = threadIdx.x;
    const int lane = tid & 63;
    const int wid  = tid >> 6;
    const int wrow = wid >> 1;
    const int wcol = wid & 1;
    const int m0 = blockIdx.x * 128;
    const int n0 = blockIdx.y * 128;

    f32x4 acc[4][4] = {};

    #define STAGE(kb)                                                          \
        _Pragma("unroll")                                                      \
        for (int k = 0; k < 4; ++k) {                                          \
            int idx = k*256 + tid;                                             \
            int row = idx >> 3, s = idx & 7;                                   \
            int sc = s ^ (row & 7);                                            \
            gload16(A  + (size_t)(m0+row)*1024 + (kb) + sc*8, As + idx*16);    \
            gload16(Bw + (size_t)(n0+row)*1024 + (kb) + sc*8, Bs + idx*16);    \
        }

    STAGE(0)
    for (int kt = 0; kt < 16; ++kt) {
        __syncthreads();
        #pragma unroll
        for (int ks = 0; ks < 2; ++ks) {
            bf16x8 af[4], bfr[4];
            #pragma unroll
            for (int i = 0; i < 4; ++i) {
                int row = wrow*64 + i*16 + (lane & 15);
                int sl  = ks*4 + (lane >> 4);
                af[i] = *(const bf16x8*)(As + row*128 + ((sl ^ (row & 7)) << 4));
            }
            #pragma unroll
            for (int j = 0; j < 4; ++j) {
                int row = wcol*64 + j*16 + (lane & 15);
                int sl  = ks*4 + (lane >> 4);
                bfr[j] = *(const bf16x8*)(Bs + row*128 + ((sl ^ (row & 7)) << 4));
            }
            #pragma unroll
            for (int i = 0; i < 4; ++i)
                #pragma unroll
                for (int j = 0; j < 4; ++j)
                    acc[i][j] = MFMA16(af[i], bfr[j], acc[i][j]);
        }
        __syncthreads();
        if (kt < 15) STAGE((kt+1)*64)
    }
    #undef STAGE

    #pragma unroll
    for (int i = 0; i < 4; ++i) {
        #pragma unroll
        for (int j = 0; j < 4; ++j) {
            #pragma unroll
            for (int q = 0; q < 4; ++q) {
                int gm = m0 + wrow*64 + i*16 + (lane >> 4)*4 + q;
                int gn = n0 + wcol*64 + j*16 + (lane & 15);
                if (MODE == 1) {
                    ((float*)C0)[(size_t)gm*1024 + gn] = acc[i][j][q] + b0[gn];
                } else {
                    int reg = gn >> 10, nn = gn & 1023;
                    float bias = ((reg == 0) ? b0 : (reg == 1) ? b1 : b2)[nn];
                    float v = acc[i][j][q] + bias;
                    int b = gm >> 11, s = gm & 2047;
                    int h = nn >> 6,  dk = nn & 63;
                    int hh = b*16 + h;
                    ushort_t bv = f2bf(v);
                    if (reg == 0) {
                        ((ushort_t*)C0)[((size_t)hh*2048 + s)*64 + dk] = bv;           // Qb
                    } else if (reg == 1) {
                        ((ushort_t*)C1)[((size_t)hh*2048 + s)*64 + dk] = bv;           // Kn
                        ((ushort_t*)C2)[(((size_t)hh*4 + (s & 3))*512 + (s >> 2))*64 + dk] = bv; // Kss
                    } else {
                        ((ushort_t*)C3)[((size_t)hh*64 + dk)*2048 + s] = bv;           // Vtn
                        ((ushort_t*)C4)[(((size_t)hh*4 + (s & 3))*64 + dk)*512 + (s >> 2)] = bv; // Vts
                    }
                }
            }
        }
    }
}

// ---------------- sparse flash attention v7: LDS-staged shared K/V ----------------
// r9 diagnosis: per-wave private K/V loads = ~700MB-1.4GB of L2 requests (no
// sharing, half-line fragments) -> L2-request-bound at ~94us with all pipes idle.
// Restructure: WG = (bh, residue r, row-group g); all 4 waves share residue r's
// K/V panel -> stage each 64-col chunk ONCE into LDS (global_load_lds, coalesced,
// pre-swizzled source), double-buffered, 1 barrier/iter, prefetch-next-first.
// L2 request volume drops ~8x (4x wave sharing, 2x full-line coalescing).
// Pass 1: 8 strided chunks (unmasked). Pass 2: 5-6 local blocks (masked,
// window of the 256-row span), same staged path. Fixed-offset softmax kept.
__global__ __launch_bounds__(256, 2)
void sparse_attn7(const ushort_t* __restrict__ Qg,
                  const ushort_t* __restrict__ Kn,
                  const ushort_t* __restrict__ Kss,
                  const ushort_t* __restrict__ Vtn,
                  const ushort_t* __restrict__ Vts,
                  ushort_t* __restrict__ attn)
{
    __shared__ __align__(16) char Klds[2][8192];
    __shared__ __align__(16) char Vlds[2][8192];
    __shared__ __align__(16) char Ps[8192];
    const int tid  = threadIdx.x;
    const int lane = tid & 63;
    const int w    = tid >> 6;
    const int l15  = lane & 15;
    const int lhi  = lane >> 4;
    const int id2  = (blockIdx.x & 7)*128 + (blockIdx.x >> 3);   // XCD: 4 heads each
    const int bh   = id2 >> 5;
    const int rem  = id2 & 31;
    const int r    = rem >> 3;      // residue
    const int g    = rem & 7;       // row-group: q-rows r+4*qidx, qidx in [g*64,(g+1)*64)
    char* Pw = Ps + w*2048;

    const ushort_t* Kst = Kss + ((size_t)bh*4 + r)*512*64;   // [512 t][64 dk]
    const ushort_t* Vst = Vts + ((size_t)bh*4 + r)*64*512;   // [64 dk][512 t]
    const ushort_t* Knb = Kn  + (size_t)bh*2048*64;          // [2048][64]
    const ushort_t* Vtb = Vtn + (size_t)bh*64*2048;          // [64][2048]

    const int bl0 = (g > 0) ? 4*g - 1 : 0;
    const int bl1 = (g < 7) ? 4*g + 4 : 31;
    const int NT  = 8 + (bl1 - bl0 + 1);

    // Q A-frags: A-row m = l15 -> q-row = r + 4*(g*64 + w*16 + m)
    bf16x8 aq[2];
    {
        const ushort_t* qp = Qg + ((size_t)bh*2048 + r + 4*(g*64 + w*16 + l15))*64 + lhi*8;
        aq[0] = *(const bf16x8*)(qp);
        aq[1] = *(const bf16x8*)(qp + 32);
    }

    float tsum[4] = {0.f, 0.f, 0.f, 0.f};
    f32x4 oacc[4] = {};

    // stage chunk t into buffer b: 64 rows x 128B each for K and V, source
    // pre-swizzled (slot sc = s ^ (row&7)) so swizzled ds_read matches (rule 21).
    #define ASTAGE(t, b)                                                         \
        _Pragma("unroll")                                                        \
        for (int k = 0; k < 2; ++k) {                                            \
            int idx = k*256 + tid;                                               \
            int row = idx >> 3, s = idx & 7;                                     \
            int sc = s ^ (row & 7);                                              \
            if ((t) < 8) {                                                       \
                gload16(Kst + (size_t)((t)*64 + row)*64 + sc*8, &Klds[b][idx*16]); \
                gload16(Vst + (size_t)row*512 + (t)*64 + sc*8, &Vlds[b][idx*16]); \
            } else {                                                             \
                int bl = bl0 + (t) - 8;                                          \
                gload16(Knb + (size_t)(bl*64 + row)*64 + sc*8, &Klds[b][idx*16]); \
                gload16(Vtb + (size_t)row*2048 + bl*64 + sc*8, &Vlds[b][idx*16]); \
            }                                                                    \
        }

    ASTAGE(0, 0)
    int cur = 0;
    for (int t = 0; t < NT; ++t) {
        __syncthreads();                       // drains vmcnt: chunk t visible
        if (t + 1 < NT) ASTAGE(t + 1, cur ^ 1)
        // ---- QK^T from Klds[cur] ----
        f32x4 sacc[4] = {};
        #pragma unroll
        for (int ks = 0; ks < 2; ++ks) {
            bf16x8 bk[4];
            #pragma unroll
            for (int n = 0; n < 4; ++n) {
                int row = n*16 + l15;
                int sl  = ks*4 + lhi;
                bk[n] = *(const bf16x8*)(&Klds[cur][row*128 + ((sl ^ (row & 7)) << 4)]);
            }
            #pragma unroll
            for (int n = 0; n < 4; ++n)
                sacc[n] = MFMA16(aq[ks], bk[n], sacc[n]);
        }
        // ---- softmax (fixed offset), P -> wave-private LDS ----
        if (t < 8) {
            #pragma unroll
            for (int n = 0; n < 4; ++n) {
                int colb = (n*16 + l15) * 2;
                #pragma unroll
                for (int q = 0; q < 4; ++q) {
                    float p = __expf(sacc[n][q]*0.125f - 16.f);
                    tsum[q] += p;
                    int rowp = lhi*4 + q;
                    *(__bf16*)(Pw + rowp*128 + (colb ^ ((rowp & 7) << 4))) = (__bf16)p;
                }
            }
        } else {
            int bl = bl0 + t - 8;
            bool notstr = ((l15 & 3) != r);
            #pragma unroll
            for (int n = 0; n < 4; ++n) {
                int j = bl*64 + n*16 + l15;
                int colb = (n*16 + l15) * 2;
                #pragma unroll
                for (int q = 0; q < 4; ++q) {
                    int i = r + 4*(g*64 + w*16 + 4*lhi + q);
                    int d = j - i;
                    bool valid = notstr && (d <= 32) && (d >= -32);
                    float sv = valid ? sacc[n][q]*0.125f : -1e30f;
                    float p = __expf(sv - 16.f);
                    tsum[q] += p;
                    int rowp = lhi*4 + q;
                    *(__bf16*)(Pw + rowp*128 + (colb ^ ((rowp & 7) << 4))) = (__bf16)p;
                }
            }
        }
        // ---- PV from Vlds[cur] ----
        #pragma unroll
        for (int ks = 0; ks < 2; ++ks) {
            int sl = ks*4 + lhi;
            bf16x8 pf = *(const bf16x8*)(Pw + l15*128 + ((sl ^ (l15 & 7)) << 4));
            #pragma unroll
            for (int d = 0; d < 4; ++d) {
                int rowv = d*16 + l15;
                bf16x8 vf = *(const bf16x8*)(&Vlds[cur][rowv*128 + ((sl ^ (rowv & 7)) << 4)]);
                oacc[d] = MFMA16(pf, vf, oacc[d]);
            }
        }
        cur ^= 1;
    }
    #undef ASTAGE

    // ---- epilogue: single deferred row-sum reduction + normalize ----
    const int b = bh >> 4, h = bh & 15;
    f32x4 invv;
    #pragma unroll
    for (int q = 0; q < 4; ++q) {
        float t = tsum[q];
        t += __shfl_xor(t, 1);
        t += __shfl_xor(t, 2);
        t += __shfl_xor(t, 4);
        t += __shfl_xor(t, 8);
        invv[q] = 1.f / t;
    }
    #pragma unroll
    for (int d = 0; d < 4; ++d) {
        f32x4 o = oacc[d] * invv;
        #pragma unroll
        for (int q = 0; q < 4; ++q) {
            int srow = r + 4*(g*64 + w*16 + 4*lhi + q);
            int gr = b*2048 + srow;
            int gc = h*64 + d*16 + l15;
            attn[(size_t)gr*1024 + gc] = f2bf(o[q]);
        }
    }
}

extern "C" void kernel_launch(void* const* d_in, const int* in_sizes, int n_in,
                              void* d_out, int out_size, void* d_ws, size_t ws_size,
                              hipStream_t stream)
{
    const float* x  = (const float*)d_in[0];
    const float* Wq = (const float*)d_in[1];
    const float* bq = (const float*)d_in[2];
    const float* Wk = (const float*)d_in[3];
    const float* bk = (const float*)d_in[4];
    const float* Wv = (const float*)d_in[5];
    const float* bv = (const float*)d_in[6];
    const float* Wo = (const float*)d_in[7];
    const float* bo = (const float*)d_in[8];

    char* ws = (char*)d_ws;
    ushort_t* xbf  = (ushort_t*)(ws);                        // 8 MB
    ushort_t* wqkv = (ushort_t*)(ws + ((size_t)8  << 20));   // 6 MB [3072][1024]
    ushort_t* wob  = (ushort_t*)(ws + ((size_t)14 << 20));   // 2 MB
    ushort_t* Qb   = (ushort_t*)(ws + ((size_t)16 << 20));   // 8 MB [BH,S,Dk]
    ushort_t* Kn   = (ushort_t*)(ws + ((size_t)24 << 20));   // 8 MB [BH,S,Dk]
    ushort_t* Kss  = (ushort_t*)(ws + ((size_t)32 << 20));   // 8 MB [BH,4,512,64]
    ushort_t* Vtn  = (ushort_t*)(ws + ((size_t)40 << 20));   // 8 MB [BH,Dk,S]
    ushort_t* Vts  = (ushort_t*)(ws + ((size_t)48 << 20));   // 8 MB [BH,4,64,512]
    ushort_t* attn = (ushort_t*)(ws + ((size_t)56 << 20));   // 8 MB

    cast_all<<<8192, 256, 0, stream>>>(x, Wq, Wk, Wv, Wo, xbf, wqkv, wob);

    gemm_bt<0><<<dim3(32, 24), 256, 0, stream>>>(xbf, wqkv, bq, bk, bv,
                                                 Qb, Kn, Kss, Vtn, Vts);

    sparse_attn7<<<dim3(1024), 256, 0, stream>>>(Qb, Kn, Kss, Vtn, Vts, attn);

    gemm_bt<1><<<dim3(32, 8), 256, 0, stream>>>(attn, wob, bo, nullptr, nullptr,
                                                d_out, nullptr, nullptr, nullptr, nullptr);
}

// Round 11
// 105.203 us; speedup vs baseline: 2.0568x; 1.0403x over previous
//
#include <hip/hip_runtime.h>

typedef unsigned short ushort_t;
typedef __bf16 bf16x8 __attribute__((ext_vector_type(8)));
typedef float  f32x4  __attribute__((ext_vector_type(4)));

#define MFMA16(a,b,c) __builtin_amdgcn_mfma_f32_16x16x32_bf16((a),(b),(c),0,0,0)

__device__ __forceinline__ ushort_t f2bf(float f) {
    union { float f; unsigned u; } x; x.f = f;
    unsigned r = (x.u + 0x7fffu + ((x.u >> 16) & 1u)) >> 16;
    return (ushort_t)r;
}

__device__ __forceinline__ void gload16(const ushort_t* g, char* l) {
    __builtin_amdgcn_global_load_lds(
        (const __attribute__((address_space(1))) unsigned*)g,
        (__attribute__((address_space(3))) unsigned*)l, 16, 0, 0);
}

// ---------------- all casts in one launch ----------------
__global__ void cast_all(const float* __restrict__ x,
                         const float* __restrict__ Wq, const float* __restrict__ Wk,
                         const float* __restrict__ Wv, const float* __restrict__ Wo,
                         ushort_t* __restrict__ xbf, ushort_t* __restrict__ wqkv,
                         ushort_t* __restrict__ wob) {
    int i = blockIdx.x * 256 + threadIdx.x;
    float4 v;
    if (i < 1048576) {
        v = ((const float4*)x)[i];
        ushort4 o;
        o.x = f2bf(v.x); o.y = f2bf(v.y); o.z = f2bf(v.z); o.w = f2bf(v.w);
        ((ushort4*)xbf)[i] = o;
    } else {
        int j = i - 1048576;
        int r = j >> 18, jj = j & 0x3ffff;
        const float* src = (r == 0) ? Wq : (r == 1) ? Wk : (r == 2) ? Wv : Wo;
        v = ((const float4*)src)[jj];
        ushort4 o;
        o.x = f2bf(v.x); o.y = f2bf(v.y); o.z = f2bf(v.z); o.w = f2bf(v.w);
        if (r < 3) ((ushort4*)wqkv)[(size_t)r*262144 + jj] = o;
        else       ((ushort4*)wob)[jj] = o;
    }
}

// ---------------- GEMM v2: 2-phase double-buffered pipeline (T3) ----------------
// C[m,n] = sum_k A[m,k]*W[n,k] (+bias). 128x128 tile, BK=64, 256 thr (4 waves).
// Per K-step: issue STAGE(t+1) into the idle buffer FIRST, then ds_read+MFMA on
// the current buffer, then ONE barrier (compiler's vmcnt(0)+lgkmcnt(0) drain
// lands after the loads had a full compute phase in flight). Ping-pong unrolled
// with static buffer names (no runtime-indexed LDS pointers).
// MODE 0: NW=3072 QKV fused epilogue; MODE 1: NW=1024 fp32 out.
template<int MODE>
__global__ __launch_bounds__(256, 2)
void gemm_bt(const ushort_t* __restrict__ A,
             const ushort_t* __restrict__ Bw,
             const float* __restrict__ b0, const float* __restrict__ b1,
             const float* __restrict__ b2,
             void* __restrict__ C0, void* __restrict__ C1,
             void* __restrict__ C2, void* __restrict__ C3,
             void* __restrict__ C4)
{
    __shared__ __align__(16) char lds[65536];
    char* const As0 = lds;
    char* const Bs0 = lds + 16384;
    char* const As1 = lds + 32768;
    char* const Bs1 = lds + 49152;
    const int tid  = threadIdx.x;
    const int lane = tid & 63;
    const int wid  = tid >> 6;
    const int wrow = wid >> 1;
    const int wcol = wid & 1;
    const int m0 = blockIdx.x * 128;
    const int n0 = blockIdx.y * 128;

    f32x4 acc[4][4] = {};

    #define STAGE(dA, dB, kb)                                                  \
        _Pragma("unroll")                                                      \
        for (int k = 0; k < 4; ++k) {                                          \
            int idx = k*256 + tid;                                             \
            int row = idx >> 3, s = idx & 7;                                   \
            int sc = s ^ (row & 7);                                            \
            gload16(A  + (size_t)(m0+row)*1024 + (kb) + sc*8, (dA) + idx*16);  \
            gload16(Bw + (size_t)(n0+row)*1024 + (kb) + sc*8, (dB) + idx*16);  \
        }

    #define COMPUTE(sA, sB)                                                    \
        _Pragma("unroll")                                                      \
        for (int ks = 0; ks < 2; ++ks) {                                       \
            bf16x8 af[4], bfr[4];                                              \
            _Pragma("unroll")                                                  \
            for (int i = 0; i < 4; ++i) {                                      \
                int row = wrow*64 + i*16 + (lane & 15);                        \
                int sl  = ks*4 + (lane >> 4);                                  \
                af[i] = *(const bf16x8*)((sA) + row*128 + ((sl ^ (row & 7)) << 4)); \
            }                                                                  \
            _Pragma("unroll")                                                  \
            for (int j = 0; j < 4; ++j) {                                      \
                int row = wcol*64 + j*16 + (lane & 15);                        \
                int sl  = ks*4 + (lane >> 4);                                  \
                bfr[j] = *(const bf16x8*)((sB) + row*128 + ((sl ^ (row & 7)) << 4)); \
            }                                                                  \
            _Pragma("unroll")                                                  \
            for (int i = 0; i < 4; ++i)                                        \
                _Pragma("unroll")                                              \
                for (int j = 0; j < 4; ++j)                                    \
                    acc[i][j] = MFMA16(af[i], bfr[j], acc[i][j]);              \
        }

    STAGE(As0, Bs0, 0)
    __syncthreads();                          // publish tile 0
    #pragma unroll
    for (int kt2 = 0; kt2 < 8; ++kt2) {
        // phase A: compute buf0, prefetch tile (2*kt2+1) into buf1
        if (2*kt2 + 1 < 16) STAGE(As1, Bs1, (2*kt2+1)*64)
        COMPUTE(As0, Bs0)
        __syncthreads();                      // drain prefetch + publish buf1
        // phase B: compute buf1, prefetch tile (2*kt2+2) into buf0
        if (2*kt2 + 2 < 16) STAGE(As0, Bs0, (2*kt2+2)*64)
        COMPUTE(As1, Bs1)
        __syncthreads();                      // drain prefetch + publish buf0
    }
    #undef STAGE
    #undef COMPUTE

    #pragma unroll
    for (int i = 0; i < 4; ++i) {
        #pragma unroll
        for (int j = 0; j < 4; ++j) {
            #pragma unroll
            for (int q = 0; q < 4; ++q) {
                int gm = m0 + wrow*64 + i*16 + (lane >> 4)*4 + q;
                int gn = n0 + wcol*64 + j*16 + (lane & 15);
                if (MODE == 1) {
                    ((float*)C0)[(size_t)gm*1024 + gn] = acc[i][j][q] + b0[gn];
                } else {
                    int reg = gn >> 10, nn = gn & 1023;
                    float bias = ((reg == 0) ? b0 : (reg == 1) ? b1 : b2)[nn];
                    float v = acc[i][j][q] + bias;
                    int b = gm >> 11, s = gm & 2047;
                    int h = nn >> 6,  dk = nn & 63;
                    int hh = b*16 + h;
                    ushort_t bv = f2bf(v);
                    if (reg == 0) {
                        ((ushort_t*)C0)[((size_t)hh*2048 + s)*64 + dk] = bv;           // Qb
                    } else if (reg == 1) {
                        ((ushort_t*)C1)[((size_t)hh*2048 + s)*64 + dk] = bv;           // Kn
                        ((ushort_t*)C2)[(((size_t)hh*4 + (s & 3))*512 + (s >> 2))*64 + dk] = bv; // Kss
                    } else {
                        ((ushort_t*)C3)[((size_t)hh*64 + dk)*2048 + s] = bv;           // Vtn
                        ((ushort_t*)C4)[(((size_t)hh*4 + (s & 3))*64 + dk)*512 + (s >> 2)] = bv; // Vts
                    }
                }
            }
        }
    }
}

// ---------------- sparse flash attention v7 (unchanged from r10) ----------------
__global__ __launch_bounds__(256, 2)
void sparse_attn7(const ushort_t* __restrict__ Qg,
                  const ushort_t* __restrict__ Kn,
                  const ushort_t* __restrict__ Kss,
                  const ushort_t* __restrict__ Vtn,
                  const ushort_t* __restrict__ Vts,
                  ushort_t* __restrict__ attn)
{
    __shared__ __align__(16) char Klds[2][8192];
    __shared__ __align__(16) char Vlds[2][8192];
    __shared__ __align__(16) char Ps[8192];
    const int tid  = threadIdx.x;
    const int lane = tid & 63;
    const int w    = tid >> 6;
    const int l15  = lane & 15;
    const int lhi  = lane >> 4;
    const int id2  = (blockIdx.x & 7)*128 + (blockIdx.x >> 3);   // XCD: 4 heads each
    const int bh   = id2 >> 5;
    const int rem  = id2 & 31;
    const int r    = rem >> 3;      // residue
    const int g    = rem & 7;       // row-group
    char* Pw = Ps + w*2048;

    const ushort_t* Kst = Kss + ((size_t)bh*4 + r)*512*64;   // [512 t][64 dk]
    const ushort_t* Vst = Vts + ((size_t)bh*4 + r)*64*512;   // [64 dk][512 t]
    const ushort_t* Knb = Kn  + (size_t)bh*2048*64;          // [2048][64]
    const ushort_t* Vtb = Vtn + (size_t)bh*64*2048;          // [64][2048]

    const int bl0 = (g > 0) ? 4*g - 1 : 0;
    const int bl1 = (g < 7) ? 4*g + 4 : 31;
    const int NT  = 8 + (bl1 - bl0 + 1);

    bf16x8 aq[2];
    {
        const ushort_t* qp = Qg + ((size_t)bh*2048 + r + 4*(g*64 + w*16 + l15))*64 + lhi*8;
        aq[0] = *(const bf16x8*)(qp);
        aq[1] = *(const bf16x8*)(qp + 32);
    }

    float tsum[4] = {0.f, 0.f, 0.f, 0.f};
    f32x4 oacc[4] = {};

    #define ASTAGE(t, b)                                                         \
        _Pragma("unroll")                                                        \
        for (int k = 0; k < 2; ++k) {                                            \
            int idx = k*256 + tid;                                               \
            int row = idx >> 3, s = idx & 7;                                     \
            int sc = s ^ (row & 7);                                              \
            if ((t) < 8) {                                                       \
                gload16(Kst + (size_t)((t)*64 + row)*64 + sc*8, &Klds[b][idx*16]); \
                gload16(Vst + (size_t)row*512 + (t)*64 + sc*8, &Vlds[b][idx*16]); \
            } else {                                                             \
                int bl = bl0 + (t) - 8;                                          \
                gload16(Knb + (size_t)(bl*64 + row)*64 + sc*8, &Klds[b][idx*16]); \
                gload16(Vtb + (size_t)row*2048 + bl*64 + sc*8, &Vlds[b][idx*16]); \
            }                                                                    \
        }

    ASTAGE(0, 0)
    int cur = 0;
    for (int t = 0; t < NT; ++t) {
        __syncthreads();
        if (t + 1 < NT) ASTAGE(t + 1, cur ^ 1)
        f32x4 sacc[4] = {};
        #pragma unroll
        for (int ks = 0; ks < 2; ++ks) {
            bf16x8 bk[4];
            #pragma unroll
            for (int n = 0; n < 4; ++n) {
                int row = n*16 + l15;
                int sl  = ks*4 + lhi;
                bk[n] = *(const bf16x8*)(&Klds[cur][row*128 + ((sl ^ (row & 7)) << 4)]);
            }
            #pragma unroll
            for (int n = 0; n < 4; ++n)
                sacc[n] = MFMA16(aq[ks], bk[n], sacc[n]);
        }
        if (t < 8) {
            #pragma unroll
            for (int n = 0; n < 4; ++n) {
                int colb = (n*16 + l15) * 2;
                #pragma unroll
                for (int q = 0; q < 4; ++q) {
                    float p = __expf(sacc[n][q]*0.125f - 16.f);
                    tsum[q] += p;
                    int rowp = lhi*4 + q;
                    *(__bf16*)(Pw + rowp*128 + (colb ^ ((rowp & 7) << 4))) = (__bf16)p;
                }
            }
        } else {
            int bl = bl0 + t - 8;
            bool notstr = ((l15 & 3) != r);
            #pragma unroll
            for (int n = 0; n < 4; ++n) {
                int j = bl*64 + n*16 + l15;
                int colb = (n*16 + l15) * 2;
                #pragma unroll
                for (int q = 0; q < 4; ++q) {
                    int i = r + 4*(g*64 + w*16 + 4*lhi + q);
                    int d = j - i;
                    bool valid = notstr && (d <= 32) && (d >= -32);
                    float sv = valid ? sacc[n][q]*0.125f : -1e30f;
                    float p = __expf(sv - 16.f);
                    tsum[q] += p;
                    int rowp = lhi*4 + q;
                    *(__bf16*)(Pw + rowp*128 + (colb ^ ((rowp & 7) << 4))) = (__bf16)p;
                }
            }
        }
        #pragma unroll
        for (int ks = 0; ks < 2; ++ks) {
            int sl = ks*4 + lhi;
            bf16x8 pf = *(const bf16x8*)(Pw + l15*128 + ((sl ^ (l15 & 7)) << 4));
            #pragma unroll
            for (int d = 0; d < 4; ++d) {
                int rowv = d*16 + l15;
                bf16x8 vf = *(const bf16x8*)(&Vlds[cur][rowv*128 + ((sl ^ (rowv & 7)) << 4)]);
                oacc[d] = MFMA16(pf, vf, oacc[d]);
            }
        }
        cur ^= 1;
    }
    #undef ASTAGE

    const int b = bh >> 4, h = bh & 15;
    f32x4 invv;
    #pragma unroll
    for (int q = 0; q < 4; ++q) {
        float t = tsum[q];
        t += __shfl_xor(t, 1);
        t += __shfl_xor(t, 2);
        t += __shfl_xor(t, 4);
        t += __shfl_xor(t, 8);
        invv[q] = 1.f / t;
    }
    #pragma unroll
    for (int d = 0; d < 4; ++d) {
        f32x4 o = oacc[d] * invv;
        #pragma unroll
        for (int q = 0; q < 4; ++q) {
            int srow = r + 4*(g*64 + w*16 + 4*lhi + q);
            int gr = b*2048 + srow;
            int gc = h*64 + d*16 + l15;
            attn[(size_t)gr*1024 + gc] = f2bf(o[q]);
        }
    }
}

extern "C" void kernel_launch(void* const* d_in, const int* in_sizes, int n_in,
                              void* d_out, int out_size, void* d_ws, size_t ws_size,
                              hipStream_t stream)
{
    const float* x  = (const float*)d_in[0];
    const float* Wq = (const float*)d_in[1];
    const float* bq = (const float*)d_in[2];
    const float* Wk = (const float*)d_in[3];
    const float* bk = (const float*)d_in[4];
    const float* Wv = (const float*)d_in[5];
    const float* bv = (const float*)d_in[6];
    const float* Wo = (const float*)d_in[7];
    const float* bo = (const float*)d_in[8];

    char* ws = (char*)d_ws;
    ushort_t* xbf  = (ushort_t*)(ws);                        // 8 MB
    ushort_t* wqkv = (ushort_t*)(ws + ((size_t)8  << 20));   // 6 MB [3072][1024]
    ushort_t* wob  = (ushort_t*)(ws + ((size_t)14 << 20));   // 2 MB
    ushort_t* Qb   = (ushort_t*)(ws + ((size_t)16 << 20));   // 8 MB [BH,S,Dk]
    ushort_t* Kn   = (ushort_t*)(ws + ((size_t)24 << 20));   // 8 MB [BH,S,Dk]
    ushort_t* Kss  = (ushort_t*)(ws + ((size_t)32 << 20));   // 8 MB [BH,4,512,64]
    ushort_t* Vtn  = (ushort_t*)(ws + ((size_t)40 << 20));   // 8 MB [BH,Dk,S]
    ushort_t* Vts  = (ushort_t*)(ws + ((size_t)48 << 20));   // 8 MB [BH,4,64,512]
    ushort_t* attn = (ushort_t*)(ws + ((size_t)56 << 20));   // 8 MB

    cast_all<<<8192, 256, 0, stream>>>(x, Wq, Wk, Wv, Wo, xbf, wqkv, wob);

    gemm_bt<0><<<dim3(32, 24), 256, 0, stream>>>(xbf, wqkv, bq, bk, bv,
                                                 Qb, Kn, Kss, Vtn, Vts);

    sparse_attn7<<<dim3(1024), 256, 0, stream>>>(Qb, Kn, Kss, Vtn, Vts, attn);

    gemm_bt<1><<<dim3(32, 8), 256, 0, stream>>>(attn, wob, bo, nullptr, nullptr,
                                                d_out, nullptr, nullptr, nullptr, nullptr);
}

// Round 12
// 94.503 us; speedup vs baseline: 2.2897x; 1.1132x over previous
//
#include <hip/hip_runtime.h>

typedef unsigned short ushort_t;
typedef __bf16 bf16x8 __attribute__((ext_vector_type(8)));
typedef float  f32x4  __attribute__((ext_vector_type(4)));

#define MFMA16(a,b,c) __builtin_amdgcn_mfma_f32_16x16x32_bf16((a),(b),(c),0,0,0)

__device__ __forceinline__ ushort_t f2bf(float f) {
    union { float f; unsigned u; } x; x.f = f;
    unsigned r = (x.u + 0x7fffu + ((x.u >> 16) & 1u)) >> 16;
    return (ushort_t)r;
}

__device__ __forceinline__ void gload16(const ushort_t* g, char* l) {
    __builtin_amdgcn_global_load_lds(
        (const __attribute__((address_space(1))) unsigned*)g,
        (__attribute__((address_space(3))) unsigned*)l, 16, 0, 0);
}

// ---------------- all casts in one launch ----------------
__global__ void cast_all(const float* __restrict__ x,
                         const float* __restrict__ Wq, const float* __restrict__ Wk,
                         const float* __restrict__ Wv, const float* __restrict__ Wo,
                         ushort_t* __restrict__ xbf, ushort_t* __restrict__ wqkv,
                         ushort_t* __restrict__ wob) {
    int i = blockIdx.x * 256 + threadIdx.x;
    float4 v;
    if (i < 1048576) {
        v = ((const float4*)x)[i];
        ushort4 o;
        o.x = f2bf(v.x); o.y = f2bf(v.y); o.z = f2bf(v.z); o.w = f2bf(v.w);
        ((ushort4*)xbf)[i] = o;
    } else {
        int j = i - 1048576;
        int r = j >> 18, jj = j & 0x3ffff;
        const float* src = (r == 0) ? Wq : (r == 1) ? Wk : (r == 2) ? Wv : Wo;
        v = ((const float4*)src)[jj];
        ushort4 o;
        o.x = f2bf(v.x); o.y = f2bf(v.y); o.z = f2bf(v.z); o.w = f2bf(v.w);
        if (r < 3) ((ushort4*)wqkv)[(size_t)r*262144 + jj] = o;
        else       ((ushort4*)wob)[jj] = o;
    }
}

// ---------------- GEMM v3: r10 single-buffer loop + LDS-staged coalesced epilogue ----
// C[m,n] = sum_k A[m,k]*W[n,k] (+bias). 128x128 tile, BK=64, 256 thr (4 waves 2x2).
// r11 post-mortem: QKV was WRITE-bound (77MB vs 24MB unique, 2B scatters).
// MODE 0 (QKV): write ONLY Q [hh][s][dk], Kss [hh][r'][t][dk], Vts [hh][r'][dk][t]
// (24MB unique) via per-wave 64x64 LDS staging -> 16B/lane coalesced stores.
// MODE 1: fp32 direct out.
template<int MODE>
__global__ void gemm_bt(const ushort_t* __restrict__ A,
                        const ushort_t* __restrict__ Bw,
                        const float* __restrict__ b0, const float* __restrict__ b1,
                        const float* __restrict__ b2,
                        void* __restrict__ C0, void* __restrict__ C1,
                        void* __restrict__ C2)
{
    __shared__ __align__(16) char lds[32768];
    char* As = lds;
    char* Bs = lds + 16384;
    const int tid  = threadIdx.x;
    const int lane = tid & 63;
    const int wid  = tid >> 6;
    const int wrow = wid >> 1;
    const int wcol = wid & 1;
    const int l15  = lane & 15;
    const int lhi  = lane >> 4;
    const int m0 = blockIdx.x * 128;
    const int n0 = blockIdx.y * 128;

    f32x4 acc[4][4] = {};

    #define STAGE(kb)                                                          \
        _Pragma("unroll")                                                      \
        for (int k = 0; k < 4; ++k) {                                          \
            int idx = k*256 + tid;                                             \
            int row = idx >> 3, s = idx & 7;                                   \
            int sc = s ^ (row & 7);                                            \
            gload16(A  + (size_t)(m0+row)*1024 + (kb) + sc*8, As + idx*16);    \
            gload16(Bw + (size_t)(n0+row)*1024 + (kb) + sc*8, Bs + idx*16);    \
        }

    STAGE(0)
    for (int kt = 0; kt < 16; ++kt) {
        __syncthreads();
        #pragma unroll
        for (int ks = 0; ks < 2; ++ks) {
            bf16x8 af[4], bfr[4];
            #pragma unroll
            for (int i = 0; i < 4; ++i) {
                int row = wrow*64 + i*16 + l15;
                int sl  = ks*4 + lhi;
                af[i] = *(const bf16x8*)(As + row*128 + ((sl ^ (row & 7)) << 4));
            }
            #pragma unroll
            for (int j = 0; j < 4; ++j) {
                int row = wcol*64 + j*16 + l15;
                int sl  = ks*4 + lhi;
                bfr[j] = *(const bf16x8*)(Bs + row*128 + ((sl ^ (row & 7)) << 4));
            }
            #pragma unroll
            for (int i = 0; i < 4; ++i)
                #pragma unroll
                for (int j = 0; j < 4; ++j)
                    acc[i][j] = MFMA16(af[i], bfr[j], acc[i][j]);
        }
        __syncthreads();
        if (kt < 15) STAGE((kt+1)*64)
    }
    #undef STAGE

    if (MODE == 1) {
        #pragma unroll
        for (int i = 0; i < 4; ++i)
            #pragma unroll
            for (int j = 0; j < 4; ++j)
                #pragma unroll
                for (int q = 0; q < 4; ++q) {
                    int gm = m0 + wrow*64 + i*16 + lhi*4 + q;
                    int gn = n0 + wcol*64 + j*16 + l15;
                    ((float*)C0)[(size_t)gm*1024 + gn] = acc[i][j][q] + b0[gn];
                }
        return;
    }

    // ---- MODE 0 epilogue: LDS-staged, coalesced ----
    const int reg  = n0 >> 10;                         // 0=Q, 1=K, 2=V
    const int nnw0 = (n0 & 1023) + wcol*64;            // bias base for this wave
    const int h    = nnw0 >> 6;                        // head (uniform per wave)
    const int b    = (m0 + wrow*64) >> 11;
    const int s0w  = (m0 + wrow*64) & 2047;            // 64 s-rows, mult of 64
    const size_t hh = (size_t)b*16 + h;
    const float* bp = (reg == 0) ? b0 : (reg == 1) ? b1 : b2;
    char* Cw = lds + wid*8192;                         // per-wave 64x128B region

    // write phase: acc -> LDS (swizzled slots). V-region stored transposed with
    // permuted cols colp = q*16 + i*4 + lhi so the read phase emits contiguous
    // [r'][t] runs.
    if (reg == 2) {
        #pragma unroll
        for (int i = 0; i < 4; ++i)
            #pragma unroll
            for (int j = 0; j < 4; ++j)
                #pragma unroll
                for (int q = 0; q < 4; ++q) {
                    float v = acc[i][j][q] + bp[nnw0 + j*16 + l15];
                    int rowl = j*16 + l15;             // dk
                    int cb = (q*16 + i*4 + lhi) * 2;   // permuted s-local * 2B
                    *(__bf16*)(Cw + rowl*128 + (cb & 15) + ((((cb >> 4)) ^ (rowl & 7)) << 4)) = (__bf16)v;
                }
    } else {
        #pragma unroll
        for (int i = 0; i < 4; ++i)
            #pragma unroll
            for (int j = 0; j < 4; ++j)
                #pragma unroll
                for (int q = 0; q < 4; ++q) {
                    float v = acc[i][j][q] + bp[nnw0 + j*16 + l15];
                    int rowl = i*16 + lhi*4 + q;       // s-local
                    int cb = (j*16 + l15) * 2;         // dk * 2B
                    *(__bf16*)(Cw + rowl*128 + (cb & 15) + ((((cb >> 4)) ^ (rowl & 7)) << 4)) = (__bf16)v;
                }
    }
    __syncthreads();

    // read+store phase: 16B per lane, fully coalesced per destination layout
    const int rowr = lane >> 3;
    const int sl2  = lane & 7;
    #pragma unroll
    for (int p = 0; p < 8; ++p) {
        int row = p*8 + rowr;
        bf16x8 val = *(const bf16x8*)(Cw + row*128 + ((sl2 ^ (row & 7)) << 4));
        ushort_t* dst;
        if (reg == 0) {
            dst = (ushort_t*)C0 + (hh*2048 + s0w + row)*64 + sl2*8;
        } else if (reg == 1) {
            dst = (ushort_t*)C1 + ((hh*4 + (row & 3))*512 + (s0w >> 2) + (row >> 2))*64 + sl2*8;
        } else {
            dst = (ushort_t*)C2 + ((hh*4 + (sl2 >> 1))*64 + row)*512 + (s0w >> 2) + (sl2 & 1)*8;
        }
        *(bf16x8*)dst = val;
    }
}

// ---------------- sparse flash attention v8: both passes from residue panels ----
// Pass 1: as before (residue r panel, unmasked). Pass 2: chunks gathered from
// Kss/Vts with the SAME per-chunk permutation pr=(r'',tl) on K-rows, P-cols and
// V-cols: score col pr = n*16+l15 <-> j = 4*(bl*16+l15)+n. Mask: (n!=r) && |j-i|<=32.
__global__ __launch_bounds__(256, 2)
void sparse_attn8(const ushort_t* __restrict__ Qg,
                  const ushort_t* __restrict__ Kss,
                  const ushort_t* __restrict__ Vts,
                  ushort_t* __restrict__ attn)
{
    __shared__ __align__(16) char Klds[2][8192];
    __shared__ __align__(16) char Vlds[2][8192];
    __shared__ __align__(16) char Ps[8192];
    const int tid  = threadIdx.x;
    const int lane = tid & 63;
    const int w    = tid >> 6;
    const int l15  = lane & 15;
    const int lhi  = lane >> 4;
    const int id2  = (blockIdx.x & 7)*128 + (blockIdx.x >> 3);   // XCD: 4 heads each
    const int bh   = id2 >> 5;
    const int rem  = id2 & 31;
    const int r    = rem >> 3;      // residue
    const int g    = rem & 7;       // row-group
    char* Pw = Ps + w*2048;

    const ushort_t* Kst0 = Kss + (size_t)bh*4*512*64;        // 4 panels [512][64]
    const ushort_t* Vts0 = Vts + (size_t)bh*4*64*512;        // 4 panels [64][512]
    const ushort_t* Kst  = Kst0 + (size_t)r*512*64;
    const ushort_t* Vst  = Vts0 + (size_t)r*64*512;

    const int bl0 = (g > 0) ? 4*g - 1 : 0;
    const int bl1 = (g < 7) ? 4*g + 4 : 31;
    const int NT  = 8 + (bl1 - bl0 + 1);

    bf16x8 aq[2];
    {
        const ushort_t* qp = Qg + ((size_t)bh*2048 + r + 4*(g*64 + w*16 + l15))*64 + lhi*8;
        aq[0] = *(const bf16x8*)(qp);
        aq[1] = *(const bf16x8*)(qp + 32);
    }

    float tsum[4] = {0.f, 0.f, 0.f, 0.f};
    f32x4 oacc[4] = {};

    #define ASTAGE(t, b)                                                           \
        _Pragma("unroll")                                                          \
        for (int k = 0; k < 2; ++k) {                                              \
            int idx = k*256 + tid;                                                 \
            int row = idx >> 3, s = idx & 7;                                       \
            int sc = s ^ (row & 7);                                                \
            if ((t) < 8) {                                                         \
                gload16(Kst + (size_t)((t)*64 + row)*64 + sc*8, &Klds[b][idx*16]); \
                gload16(Vst + (size_t)row*512 + (t)*64 + sc*8, &Vlds[b][idx*16]);  \
            } else {                                                               \
                int bl = bl0 + (t) - 8;                                            \
                gload16(Kst0 + (size_t)((row>>4)*512 + bl*16 + (row&15))*64 + sc*8,\
                        &Klds[b][idx*16]);                                         \
                gload16(Vts0 + (size_t)((sc>>1)*64 + row)*512 + bl*16 + (sc&1)*8,  \
                        &Vlds[b][idx*16]);                                         \
            }                                                                      \
        }

    ASTAGE(0, 0)
    int cur = 0;
    for (int t = 0; t < NT; ++t) {
        __syncthreads();
        if (t + 1 < NT) ASTAGE(t + 1, cur ^ 1)
        f32x4 sacc[4] = {};
        #pragma unroll
        for (int ks = 0; ks < 2; ++ks) {
            bf16x8 bk[4];
            #pragma unroll
            for (int n = 0; n < 4; ++n) {
                int row = n*16 + l15;
                int sl  = ks*4 + lhi;
                bk[n] = *(const bf16x8*)(&Klds[cur][row*128 + ((sl ^ (row & 7)) << 4)]);
            }
            #pragma unroll
            for (int n = 0; n < 4; ++n)
                sacc[n] = MFMA16(aq[ks], bk[n], sacc[n]);
        }
        if (t < 8) {
            #pragma unroll
            for (int n = 0; n < 4; ++n) {
                int colb = (n*16 + l15) * 2;
                #pragma unroll
                for (int q = 0; q < 4; ++q) {
                    float p = __expf(sacc[n][q]*0.125f - 16.f);
                    tsum[q] += p;
                    int rowp = lhi*4 + q;
                    *(__bf16*)(Pw + rowp*128 + (colb ^ ((rowp & 7) << 4))) = (__bf16)p;
                }
            }
        } else {
            int bl = bl0 + t - 8;
            #pragma unroll
            for (int n = 0; n < 4; ++n) {
                int j = 4*(bl*16 + l15) + n;          // permuted col -> natural j
                int colb = (n*16 + l15) * 2;
                bool nres = (n != r);
                #pragma unroll
                for (int q = 0; q < 4; ++q) {
                    int i = r + 4*(g*64 + w*16 + 4*lhi + q);
                    int d = j - i;
                    bool valid = nres && (d <= 32) && (d >= -32);
                    float sv = valid ? sacc[n][q]*0.125f : -1e30f;
                    float p = __expf(sv - 16.f);
                    tsum[q] += p;
                    int rowp = lhi*4 + q;
                    *(__bf16*)(Pw + rowp*128 + (colb ^ ((rowp & 7) << 4))) = (__bf16)p;
                }
            }
        }
        #pragma unroll
        for (int ks = 0; ks < 2; ++ks) {
            int sl = ks*4 + lhi;
            bf16x8 pf = *(const bf16x8*)(Pw + l15*128 + ((sl ^ (l15 & 7)) << 4));
            #pragma unroll
            for (int d = 0; d < 4; ++d) {
                int rowv = d*16 + l15;
                bf16x8 vf = *(const bf16x8*)(&Vlds[cur][rowv*128 + ((sl ^ (rowv & 7)) << 4)]);
                oacc[d] = MFMA16(pf, vf, oacc[d]);
            }
        }
        cur ^= 1;
    }
    #undef ASTAGE

    const int b = bh >> 4, h = bh & 15;
    f32x4 invv;
    #pragma unroll
    for (int q = 0; q < 4; ++q) {
        float t = tsum[q];
        t += __shfl_xor(t, 1);
        t += __shfl_xor(t, 2);
        t += __shfl_xor(t, 4);
        t += __shfl_xor(t, 8);
        invv[q] = 1.f / t;
    }
    #pragma unroll
    for (int d = 0; d < 4; ++d) {
        f32x4 o = oacc[d] * invv;
        #pragma unroll
        for (int q = 0; q < 4; ++q) {
            int srow = r + 4*(g*64 + w*16 + 4*lhi + q);
            int gr = b*2048 + srow;
            int gc = h*64 + d*16 + l15;
            attn[(size_t)gr*1024 + gc] = f2bf(o[q]);
        }
    }
}

extern "C" void kernel_launch(void* const* d_in, const int* in_sizes, int n_in,
                              void* d_out, int out_size, void* d_ws, size_t ws_size,
                              hipStream_t stream)
{
    const float* x  = (const float*)d_in[0];
    const float* Wq = (const float*)d_in[1];
    const float* bq = (const float*)d_in[2];
    const float* Wk = (const float*)d_in[3];
    const float* bk = (const float*)d_in[4];
    const float* Wv = (const float*)d_in[5];
    const float* bv = (const float*)d_in[6];
    const float* Wo = (const float*)d_in[7];
    const float* bo = (const float*)d_in[8];

    char* ws = (char*)d_ws;
    ushort_t* xbf  = (ushort_t*)(ws);                        // 8 MB
    ushort_t* wqkv = (ushort_t*)(ws + ((size_t)8  << 20));   // 6 MB [3072][1024]
    ushort_t* wob  = (ushort_t*)(ws + ((size_t)14 << 20));   // 2 MB
    ushort_t* Qb   = (ushort_t*)(ws + ((size_t)16 << 20));   // 8 MB [BH,S,Dk]
    ushort_t* Kss  = (ushort_t*)(ws + ((size_t)24 << 20));   // 8 MB [BH,4,512,64]
    ushort_t* Vts  = (ushort_t*)(ws + ((size_t)32 << 20));   // 8 MB [BH,4,64,512]
    ushort_t* attn = (ushort_t*)(ws + ((size_t)40 << 20));   // 8 MB

    cast_all<<<8192, 256, 0, stream>>>(x, Wq, Wk, Wv, Wo, xbf, wqkv, wob);

    gemm_bt<0><<<dim3(32, 24), 256, 0, stream>>>(xbf, wqkv, bq, bk, bv,
                                                 Qb, Kss, Vts);

    sparse_attn8<<<dim3(1024), 256, 0, stream>>>(Qb, Kss, Vts, attn);

    gemm_bt<1><<<dim3(32, 8), 256, 0, stream>>>(attn, wob, bo, nullptr, nullptr,
                                                d_out, nullptr, nullptr);
}

// Round 13
// 91.439 us; speedup vs baseline: 2.3664x; 1.0335x over previous
//
#include <hip/hip_runtime.h>

typedef unsigned short ushort_t;
typedef __bf16 bf16x8 __attribute__((ext_vector_type(8)));
typedef float  f32x4  __attribute__((ext_vector_type(4)));

#define MFMA16(a,b,c) __builtin_amdgcn_mfma_f32_16x16x32_bf16((a),(b),(c),0,0,0)

__device__ __forceinline__ ushort_t f2bf(float f) {
    union { float f; unsigned u; } x; x.f = f;
    unsigned r = (x.u + 0x7fffu + ((x.u >> 16) & 1u)) >> 16;
    return (ushort_t)r;
}

__device__ __forceinline__ void gload16(const ushort_t* g, char* l) {
    __builtin_amdgcn_global_load_lds(
        (const __attribute__((address_space(1))) unsigned*)g,
        (__attribute__((address_space(3))) unsigned*)l, 16, 0, 0);
}

// ---------------- all casts in one launch ----------------
__global__ void cast_all(const float* __restrict__ x,
                         const float* __restrict__ Wq, const float* __restrict__ Wk,
                         const float* __restrict__ Wv, const float* __restrict__ Wo,
                         ushort_t* __restrict__ xbf, ushort_t* __restrict__ wqkv,
                         ushort_t* __restrict__ wob) {
    int i = blockIdx.x * 256 + threadIdx.x;
    float4 v;
    if (i < 1048576) {
        v = ((const float4*)x)[i];
        ushort4 o;
        o.x = f2bf(v.x); o.y = f2bf(v.y); o.z = f2bf(v.z); o.w = f2bf(v.w);
        ((ushort4*)xbf)[i] = o;
    } else {
        int j = i - 1048576;
        int r = j >> 18, jj = j & 0x3ffff;
        const float* src = (r == 0) ? Wq : (r == 1) ? Wk : (r == 2) ? Wv : Wo;
        v = ((const float4*)src)[jj];
        ushort4 o;
        o.x = f2bf(v.x); o.y = f2bf(v.y); o.z = f2bf(v.z); o.w = f2bf(v.w);
        if (r < 3) ((ushort4*)wqkv)[(size_t)r*262144 + jj] = o;
        else       ((ushort4*)wob)[jj] = o;
    }
}

// ---------------- QKV GEMM: 128x128 tile + LDS-staged coalesced epilogue ----------
// C[m,n] = sum_k A[m,k]*W[n,k] (+bias). Writes Q (x0.125, exact bf16 exponent
// shift), Kss [hh][r'][t][dk], Vts [hh][r'][dk][t] — 24MB unique, 16B/lane stores.
__global__ void gemm_qkv(const ushort_t* __restrict__ A,
                         const ushort_t* __restrict__ Bw,
                         const float* __restrict__ b0, const float* __restrict__ b1,
                         const float* __restrict__ b2,
                         void* __restrict__ C0, void* __restrict__ C1,
                         void* __restrict__ C2)
{
    __shared__ __align__(16) char lds[32768];
    char* As = lds;
    char* Bs = lds + 16384;
    const int tid  = threadIdx.x;
    const int lane = tid & 63;
    const int wid  = tid >> 6;
    const int wrow = wid >> 1;
    const int wcol = wid & 1;
    const int l15  = lane & 15;
    const int lhi  = lane >> 4;
    const int m0 = blockIdx.x * 128;
    const int n0 = blockIdx.y * 128;

    f32x4 acc[4][4] = {};

    #define STAGE(kb)                                                          \
        _Pragma("unroll")                                                      \
        for (int k = 0; k < 4; ++k) {                                          \
            int idx = k*256 + tid;                                             \
            int row = idx >> 3, s = idx & 7;                                   \
            int sc = s ^ (row & 7);                                            \
            gload16(A  + (size_t)(m0+row)*1024 + (kb) + sc*8, As + idx*16);    \
            gload16(Bw + (size_t)(n0+row)*1024 + (kb) + sc*8, Bs + idx*16);    \
        }

    STAGE(0)
    for (int kt = 0; kt < 16; ++kt) {
        __syncthreads();
        #pragma unroll
        for (int ks = 0; ks < 2; ++ks) {
            bf16x8 af[4], bfr[4];
            #pragma unroll
            for (int i = 0; i < 4; ++i) {
                int row = wrow*64 + i*16 + l15;
                int sl  = ks*4 + lhi;
                af[i] = *(const bf16x8*)(As + row*128 + ((sl ^ (row & 7)) << 4));
            }
            #pragma unroll
            for (int j = 0; j < 4; ++j) {
                int row = wcol*64 + j*16 + l15;
                int sl  = ks*4 + lhi;
                bfr[j] = *(const bf16x8*)(Bs + row*128 + ((sl ^ (row & 7)) << 4));
            }
            #pragma unroll
            for (int i = 0; i < 4; ++i)
                #pragma unroll
                for (int j = 0; j < 4; ++j)
                    acc[i][j] = MFMA16(af[i], bfr[j], acc[i][j]);
        }
        __syncthreads();
        if (kt < 15) STAGE((kt+1)*64)
    }
    #undef STAGE

    const int reg  = n0 >> 10;                         // 0=Q, 1=K, 2=V
    const int nnw0 = (n0 & 1023) + wcol*64;
    const int h    = nnw0 >> 6;
    const int b    = (m0 + wrow*64) >> 11;
    const int s0w  = (m0 + wrow*64) & 2047;
    const size_t hh = (size_t)b*16 + h;
    const float* bp = (reg == 0) ? b0 : (reg == 1) ? b1 : b2;
    const float qsc = (reg == 0) ? 0.125f : 1.0f;      // fold 1/sqrt(Dk) into Q
    char* Cw = lds + wid*8192;

    if (reg == 2) {
        #pragma unroll
        for (int i = 0; i < 4; ++i)
            #pragma unroll
            for (int j = 0; j < 4; ++j)
                #pragma unroll
                for (int q = 0; q < 4; ++q) {
                    float v = acc[i][j][q] + bp[nnw0 + j*16 + l15];
                    int rowl = j*16 + l15;             // dk
                    int cb = (q*16 + i*4 + lhi) * 2;   // permuted s-local * 2B
                    *(__bf16*)(Cw + rowl*128 + (cb & 15) + ((((cb >> 4)) ^ (rowl & 7)) << 4)) = (__bf16)v;
                }
    } else {
        #pragma unroll
        for (int i = 0; i < 4; ++i)
            #pragma unroll
            for (int j = 0; j < 4; ++j)
                #pragma unroll
                for (int q = 0; q < 4; ++q) {
                    float v = (acc[i][j][q] + bp[nnw0 + j*16 + l15]) * qsc;
                    int rowl = i*16 + lhi*4 + q;       // s-local
                    int cb = (j*16 + l15) * 2;         // dk * 2B
                    *(__bf16*)(Cw + rowl*128 + (cb & 15) + ((((cb >> 4)) ^ (rowl & 7)) << 4)) = (__bf16)v;
                }
    }
    __syncthreads();

    const int rowr = lane >> 3;
    const int sl2  = lane & 7;
    #pragma unroll
    for (int p = 0; p < 8; ++p) {
        int row = p*8 + rowr;
        bf16x8 val = *(const bf16x8*)(Cw + row*128 + ((sl2 ^ (row & 7)) << 4));
        ushort_t* dst;
        if (reg == 0) {
            dst = (ushort_t*)C0 + (hh*2048 + s0w + row)*64 + sl2*8;
        } else if (reg == 1) {
            dst = (ushort_t*)C1 + ((hh*4 + (row & 3))*512 + (s0w >> 2) + (row >> 2))*64 + sl2*8;
        } else {
            dst = (ushort_t*)C2 + ((hh*4 + (sl2 >> 1))*64 + row)*512 + (s0w >> 2) + (sl2 & 1)*8;
        }
        *(bf16x8*)dst = val;
    }
}

// ---------------- O-proj GEMM: 64x128 tile, grid 512 = 2+/CU ----------------
// r12 diagnosis: grid 256 = exactly 1 block/CU -> zero inter-block TLP, barrier
// drain fully exposed. 64x128 tiles double the block count; LDS 24KB allows 6
// resident -> drains hide under the other block's compute.
__global__ void gemm_o(const ushort_t* __restrict__ A,
                       const ushort_t* __restrict__ Bw,
                       const float* __restrict__ b0,
                       float* __restrict__ C0)
{
    __shared__ __align__(16) char lds[24576];
    char* As = lds;              // 64 rows x 128B = 8KB
    char* Bs = lds + 8192;       // 128 rows x 128B = 16KB
    const int tid  = threadIdx.x;
    const int lane = tid & 63;
    const int wid  = tid >> 6;
    const int wrow = wid >> 1;   // 2 wave-rows of 32
    const int wcol = wid & 1;    // 2 wave-cols of 64
    const int l15  = lane & 15;
    const int lhi  = lane >> 4;
    const int m0 = blockIdx.x * 64;
    const int n0 = blockIdx.y * 128;

    f32x4 acc[2][4] = {};

    #define STAGEO(kb)                                                         \
        _Pragma("unroll")                                                      \
        for (int k = 0; k < 2; ++k) {                                          \
            int idx = k*256 + tid;                                             \
            int row = idx >> 3, s = idx & 7;                                   \
            int sc = s ^ (row & 7);                                            \
            gload16(A + (size_t)(m0+row)*1024 + (kb) + sc*8, As + idx*16);     \
        }                                                                      \
        _Pragma("unroll")                                                      \
        for (int k = 0; k < 4; ++k) {                                          \
            int idx = k*256 + tid;                                             \
            int row = idx >> 3, s = idx & 7;                                   \
            int sc = s ^ (row & 7);                                            \
            gload16(Bw + (size_t)(n0+row)*1024 + (kb) + sc*8, Bs + idx*16);    \
        }

    STAGEO(0)
    for (int kt = 0; kt < 16; ++kt) {
        __syncthreads();
        #pragma unroll
        for (int ks = 0; ks < 2; ++ks) {
            bf16x8 af[2], bfr[4];
            #pragma unroll
            for (int i = 0; i < 2; ++i) {
                int row = wrow*32 + i*16 + l15;
                int sl  = ks*4 + lhi;
                af[i] = *(const bf16x8*)(As + row*128 + ((sl ^ (row & 7)) << 4));
            }
            #pragma unroll
            for (int j = 0; j < 4; ++j) {
                int row = wcol*64 + j*16 + l15;
                int sl  = ks*4 + lhi;
                bfr[j] = *(const bf16x8*)(Bs + row*128 + ((sl ^ (row & 7)) << 4));
            }
            #pragma unroll
            for (int i = 0; i < 2; ++i)
                #pragma unroll
                for (int j = 0; j < 4; ++j)
                    acc[i][j] = MFMA16(af[i], bfr[j], acc[i][j]);
        }
        __syncthreads();
        if (kt < 15) STAGEO((kt+1)*64)
    }
    #undef STAGEO

    #pragma unroll
    for (int i = 0; i < 2; ++i)
        #pragma unroll
        for (int j = 0; j < 4; ++j)
            #pragma unroll
            for (int q = 0; q < 4; ++q) {
                int gm = m0 + wrow*32 + i*16 + lhi*4 + q;
                int gn = n0 + wcol*64 + j*16 + l15;
                C0[(size_t)gm*1024 + gn] = acc[i][j][q] + b0[gn];
            }
}

// ---------------- sparse flash attention v8b: Q pre-scaled ----------------
__global__ __launch_bounds__(256, 2)
void sparse_attn8(const ushort_t* __restrict__ Qg,
                  const ushort_t* __restrict__ Kss,
                  const ushort_t* __restrict__ Vts,
                  ushort_t* __restrict__ attn)
{
    __shared__ __align__(16) char Klds[2][8192];
    __shared__ __align__(16) char Vlds[2][8192];
    __shared__ __align__(16) char Ps[8192];
    const int tid  = threadIdx.x;
    const int lane = tid & 63;
    const int w    = tid >> 6;
    const int l15  = lane & 15;
    const int lhi  = lane >> 4;
    const int id2  = (blockIdx.x & 7)*128 + (blockIdx.x >> 3);   // XCD: 4 heads each
    const int bh   = id2 >> 5;
    const int rem  = id2 & 31;
    const int r    = rem >> 3;      // residue
    const int g    = rem & 7;       // row-group
    char* Pw = Ps + w*2048;

    const ushort_t* Kst0 = Kss + (size_t)bh*4*512*64;
    const ushort_t* Vts0 = Vts + (size_t)bh*4*64*512;
    const ushort_t* Kst  = Kst0 + (size_t)r*512*64;
    const ushort_t* Vst  = Vts0 + (size_t)r*64*512;

    const int bl0 = (g > 0) ? 4*g - 1 : 0;
    const int bl1 = (g < 7) ? 4*g + 4 : 31;
    const int NT  = 8 + (bl1 - bl0 + 1);

    bf16x8 aq[2];
    {
        const ushort_t* qp = Qg + ((size_t)bh*2048 + r + 4*(g*64 + w*16 + l15))*64 + lhi*8;
        aq[0] = *(const bf16x8*)(qp);
        aq[1] = *(const bf16x8*)(qp + 32);
    }

    float tsum[4] = {0.f, 0.f, 0.f, 0.f};
    f32x4 oacc[4] = {};

    #define ASTAGE(t, b)                                                           \
        _Pragma("unroll")                                                          \
        for (int k = 0; k < 2; ++k) {                                              \
            int idx = k*256 + tid;                                                 \
            int row = idx >> 3, s = idx & 7;                                       \
            int sc = s ^ (row & 7);                                                \
            if ((t) < 8) {                                                         \
                gload16(Kst + (size_t)((t)*64 + row)*64 + sc*8, &Klds[b][idx*16]); \
                gload16(Vst + (size_t)row*512 + (t)*64 + sc*8, &Vlds[b][idx*16]);  \
            } else {                                                               \
                int bl = bl0 + (t) - 8;                                            \
                gload16(Kst0 + (size_t)((row>>4)*512 + bl*16 + (row&15))*64 + sc*8,\
                        &Klds[b][idx*16]);                                         \
                gload16(Vts0 + (size_t)((sc>>1)*64 + row)*512 + bl*16 + (sc&1)*8,  \
                        &Vlds[b][idx*16]);                                         \
            }                                                                      \
        }

    ASTAGE(0, 0)
    int cur = 0;
    for (int t = 0; t < NT; ++t) {
        __syncthreads();
        if (t + 1 < NT) ASTAGE(t + 1, cur ^ 1)
        f32x4 sacc[4] = {};
        #pragma unroll
        for (int ks = 0; ks < 2; ++ks) {
            bf16x8 bk[4];
            #pragma unroll
            for (int n = 0; n < 4; ++n) {
                int row = n*16 + l15;
                int sl  = ks*4 + lhi;
                bk[n] = *(const bf16x8*)(&Klds[cur][row*128 + ((sl ^ (row & 7)) << 4)]);
            }
            #pragma unroll
            for (int n = 0; n < 4; ++n)
                sacc[n] = MFMA16(aq[ks], bk[n], sacc[n]);
        }
        if (t < 8) {
            #pragma unroll
            for (int n = 0; n < 4; ++n) {
                int colb = (n*16 + l15) * 2;
                #pragma unroll
                for (int q = 0; q < 4; ++q) {
                    float p = __expf(sacc[n][q] - 16.f);   // Q pre-scaled by 0.125
                    tsum[q] += p;
                    int rowp = lhi*4 + q;
                    *(__bf16*)(Pw + rowp*128 + (colb ^ ((rowp & 7) << 4))) = (__bf16)p;
                }
            }
        } else {
            int bl = bl0 + t - 8;
            #pragma unroll
            for (int n = 0; n < 4; ++n) {
                int j = 4*(bl*16 + l15) + n;
                int colb = (n*16 + l15) * 2;
                bool nres = (n != r);
                #pragma unroll
                for (int q = 0; q < 4; ++q) {
                    int i = r + 4*(g*64 + w*16 + 4*lhi + q);
                    int d = j - i;
                    bool valid = nres && (d <= 32) && (d >= -32);
                    float sv = valid ? sacc[n][q] : -1e30f;
                    float p = __expf(sv - 16.f);
                    tsum[q] += p;
                    int rowp = lhi*4 + q;
                    *(__bf16*)(Pw + rowp*128 + (colb ^ ((rowp & 7) << 4))) = (__bf16)p;
                }
            }
        }
        #pragma unroll
        for (int ks = 0; ks < 2; ++ks) {
            int sl = ks*4 + lhi;
            bf16x8 pf = *(const bf16x8*)(Pw + l15*128 + ((sl ^ (l15 & 7)) << 4));
            #pragma unroll
            for (int d = 0; d < 4; ++d) {
                int rowv = d*16 + l15;
                bf16x8 vf = *(const bf16x8*)(&Vlds[cur][rowv*128 + ((sl ^ (rowv & 7)) << 4)]);
                oacc[d] = MFMA16(pf, vf, oacc[d]);
            }
        }
        cur ^= 1;
    }
    #undef ASTAGE

    const int b = bh >> 4, h = bh & 15;
    f32x4 invv;
    #pragma unroll
    for (int q = 0; q < 4; ++q) {
        float t = tsum[q];
        t += __shfl_xor(t, 1);
        t += __shfl_xor(t, 2);
        t += __shfl_xor(t, 4);
        t += __shfl_xor(t, 8);
        invv[q] = 1.f / t;
    }
    #pragma unroll
    for (int d = 0; d < 4; ++d) {
        f32x4 o = oacc[d] * invv;
        #pragma unroll
        for (int q = 0; q < 4; ++q) {
            int srow = r + 4*(g*64 + w*16 + 4*lhi + q);
            int gr = b*2048 + srow;
            int gc = h*64 + d*16 + l15;
            attn[(size_t)gr*1024 + gc] = f2bf(o[q]);
        }
    }
}

extern "C" void kernel_launch(void* const* d_in, const int* in_sizes, int n_in,
                              void* d_out, int out_size, void* d_ws, size_t ws_size,
                              hipStream_t stream)
{
    const float* x  = (const float*)d_in[0];
    const float* Wq = (const float*)d_in[1];
    const float* bq = (const float*)d_in[2];
    const float* Wk = (const float*)d_in[3];
    const float* bk = (const float*)d_in[4];
    const float* Wv = (const float*)d_in[5];
    const float* bv = (const float*)d_in[6];
    const float* Wo = (const float*)d_in[7];
    const float* bo = (const float*)d_in[8];

    char* ws = (char*)d_ws;
    ushort_t* xbf  = (ushort_t*)(ws);                        // 8 MB
    ushort_t* wqkv = (ushort_t*)(ws + ((size_t)8  << 20));   // 6 MB [3072][1024]
    ushort_t* wob  = (ushort_t*)(ws + ((size_t)14 << 20));   // 2 MB
    ushort_t* Qb   = (ushort_t*)(ws + ((size_t)16 << 20));   // 8 MB [BH,S,Dk] (x0.125)
    ushort_t* Kss  = (ushort_t*)(ws + ((size_t)24 << 20));   // 8 MB [BH,4,512,64]
    ushort_t* Vts  = (ushort_t*)(ws + ((size_t)32 << 20));   // 8 MB [BH,4,64,512]
    ushort_t* attn = (ushort_t*)(ws + ((size_t)40 << 20));   // 8 MB

    cast_all<<<8192, 256, 0, stream>>>(x, Wq, Wk, Wv, Wo, xbf, wqkv, wob);

    gemm_qkv<<<dim3(32, 24), 256, 0, stream>>>(xbf, wqkv, bq, bk, bv,
                                               Qb, Kss, Vts);

    sparse_attn8<<<dim3(1024), 256, 0, stream>>>(Qb, Kss, Vts, attn);

    gemm_o<<<dim3(64, 8), 256, 0, stream>>>(attn, wob, bo, (float*)d_out);
}